// Round 1
// baseline (1435.279 us; speedup 1.0000x reference)
//
#include <hip/hip_runtime.h>
#include <cstdint>

#define RELU_COEF 0.05f
#define LEAKY(v) ((v) > 0.f ? (v) : RELU_COEF * (v))

// ---------------------------------------------------------------------------
// Edge scatter: agg[dst] += x[src] * w  (one thread per (edge, dim))
// ---------------------------------------------------------------------------
__global__ __launch_bounds__(256) void scatter64_kernel(
    const float* __restrict__ feat, const int* __restrict__ ei,
    const float* __restrict__ ea, float* __restrict__ agg, int E)
{
    long long gid = (long long)blockIdx.x * 256 + threadIdx.x;
    int e = (int)(gid >> 6);
    if (e >= E) return;
    int d = (int)(gid & 63);
    int s = ei[e];
    int t = ei[(size_t)E + e];
    float w = ea[e];
    atomicAdd(agg + (size_t)t * 64 + d, feat[(size_t)s * 64 + d] * w);
}

__global__ __launch_bounds__(256) void scatter128_kernel(
    const float* __restrict__ feat, const int* __restrict__ ei,
    const float* __restrict__ ea, float* __restrict__ agg, int E)
{
    long long gid = (long long)blockIdx.x * 256 + threadIdx.x;
    int e = (int)(gid >> 7);
    if (e >= E) return;
    int d = (int)(gid & 127);
    int s = ei[e];
    int t = ei[(size_t)E + e];
    float w = ea[e];
    atomicAdd(agg + (size_t)t * 128 + d, feat[(size_t)s * 128 + d] * w);
}

// ---------------------------------------------------------------------------
// Y = leaky(A1 @ W1 + A2 @ W2 + bias), A1:[n,K1] A2:[n,K2], W:[K,128], Y:[n,128]
// Tile: 64 rows x 128 cols per block; 256 threads as 16x16; 4x8 per thread.
// ---------------------------------------------------------------------------
#define BM 64
#define BKT 32

__global__ __launch_bounds__(256) void dual_linear_kernel(
    const float* __restrict__ A1, const float* __restrict__ W1, int K1,
    const float* __restrict__ A2, const float* __restrict__ W2, int K2,
    const float* __restrict__ bias, float* __restrict__ Y, int n)
{
    __shared__ float Xs[BM * 33];          // padded rows (stride 33)
    __shared__ float Ws[BKT * 128];

    int tid = threadIdx.x;
    int tx = tid & 15;        // col group: cols tx*8 .. tx*8+7
    int ty = tid >> 4;        // row group: rows ty*4 .. ty*4+3
    int i0 = blockIdx.x * BM;

    float acc[4][8];
#pragma unroll
    for (int r = 0; r < 4; ++r)
#pragma unroll
        for (int j = 0; j < 8; ++j) acc[r][j] = 0.f;

    for (int phase = 0; phase < 2; ++phase) {
        const float* A = phase ? A2 : A1;
        const float* W = phase ? W2 : W1;
        int K = phase ? K2 : K1;
        for (int kk = 0; kk < K; kk += BKT) {
            __syncthreads();
            // stage X tile: 64 x 32 (8 float4 per row)
#pragma unroll
            for (int l = 0; l < 2; ++l) {
                int idx = tid + l * 256;          // 0..511
                int m = idx >> 3;
                int kq = idx & 7;
                int row = i0 + m;
                if (row > n - 1) row = n - 1;
                const float4 v = *(const float4*)(A + (size_t)row * K + kk + kq * 4);
                float* dst = &Xs[m * 33 + kq * 4];
                dst[0] = v.x; dst[1] = v.y; dst[2] = v.z; dst[3] = v.w;
            }
            // stage W tile: 32 x 128 (32 float4 per row)
#pragma unroll
            for (int l = 0; l < 4; ++l) {
                int idx = tid + l * 256;          // 0..1023
                int kr = idx >> 5;
                int jq = idx & 31;
                const float4 v = *(const float4*)(W + (size_t)(kk + kr) * 128 + jq * 4);
                *(float4*)&Ws[kr * 128 + jq * 4] = v;
            }
            __syncthreads();
#pragma unroll
            for (int k = 0; k < BKT; ++k) {
                float xr[4];
#pragma unroll
                for (int r = 0; r < 4; ++r) xr[r] = Xs[(ty * 4 + r) * 33 + k];
                float4 w0 = *(const float4*)&Ws[k * 128 + tx * 8];
                float4 w1 = *(const float4*)&Ws[k * 128 + tx * 8 + 4];
                float wv[8] = {w0.x, w0.y, w0.z, w0.w, w1.x, w1.y, w1.z, w1.w};
#pragma unroll
                for (int r = 0; r < 4; ++r)
#pragma unroll
                    for (int j = 0; j < 8; ++j) acc[r][j] += xr[r] * wv[j];
            }
        }
    }

    float bv[8];
#pragma unroll
    for (int j = 0; j < 8; ++j) bv[j] = bias[tx * 8 + j];

#pragma unroll
    for (int r = 0; r < 4; ++r) {
        int row = i0 + ty * 4 + r;
        if (row < n) {
            float o[8];
#pragma unroll
            for (int j = 0; j < 8; ++j) {
                float v = acc[r][j] + bv[j];
                o[j] = LEAKY(v);
            }
            *(float4*)(Y + (size_t)row * 128 + tx * 8)     = make_float4(o[0], o[1], o[2], o[3]);
            *(float4*)(Y + (size_t)row * 128 + tx * 8 + 4) = make_float4(o[4], o[5], o[6], o[7]);
        }
    }
}

// ---------------------------------------------------------------------------
// Gate + pooling: per node g = sigmoid(-clip(h@Wsig+bsig)) * tanh(h@Wtanh+btanh)
// where h = [h2, x]. Then pooled[batch[i]] += g[i] with per-block run compression
// (batch is sorted).
// ---------------------------------------------------------------------------
__global__ __launch_bounds__(256) void gate_pool_kernel(
    const float* __restrict__ H2, const float* __restrict__ X,
    const float* __restrict__ Wsig, const float* __restrict__ bsig,
    const float* __restrict__ Wtanh, const float* __restrict__ btanh,
    const int* __restrict__ batch, float* __restrict__ pooled, int n)
{
    __shared__ float Xs[BM * 33];
    __shared__ float Wss[BKT * 128];
    __shared__ float Wst[BKT * 128];
    __shared__ float gs[BM * 128];
    __shared__ int bS[BM];

    int tid = threadIdx.x;
    int tx = tid & 15;
    int ty = tid >> 4;
    int i0 = blockIdx.x * BM;

    float accs[4][8], acct[4][8];
#pragma unroll
    for (int r = 0; r < 4; ++r)
#pragma unroll
        for (int j = 0; j < 8; ++j) { accs[r][j] = 0.f; acct[r][j] = 0.f; }

    for (int phase = 0; phase < 2; ++phase) {
        const float* A = phase ? X : H2;
        int K = phase ? 64 : 128;
        int rowoff = phase ? 128 : 0;   // concat([h2, x]) -> W rows 0..127 | 128..191
        for (int kk = 0; kk < K; kk += BKT) {
            __syncthreads();
#pragma unroll
            for (int l = 0; l < 2; ++l) {
                int idx = tid + l * 256;
                int m = idx >> 3;
                int kq = idx & 7;
                int row = i0 + m;
                if (row > n - 1) row = n - 1;
                const float4 v = *(const float4*)(A + (size_t)row * K + kk + kq * 4);
                float* dst = &Xs[m * 33 + kq * 4];
                dst[0] = v.x; dst[1] = v.y; dst[2] = v.z; dst[3] = v.w;
            }
#pragma unroll
            for (int l = 0; l < 4; ++l) {
                int idx = tid + l * 256;
                int kr = idx >> 5;
                int jq = idx & 31;
                size_t woff = (size_t)(rowoff + kk + kr) * 128 + jq * 4;
                *(float4*)&Wss[kr * 128 + jq * 4] = *(const float4*)(Wsig + woff);
                *(float4*)&Wst[kr * 128 + jq * 4] = *(const float4*)(Wtanh + woff);
            }
            __syncthreads();
#pragma unroll
            for (int k = 0; k < BKT; ++k) {
                float xr[4];
#pragma unroll
                for (int r = 0; r < 4; ++r) xr[r] = Xs[(ty * 4 + r) * 33 + k];
                float4 s0 = *(const float4*)&Wss[k * 128 + tx * 8];
                float4 s1 = *(const float4*)&Wss[k * 128 + tx * 8 + 4];
                float4 t0 = *(const float4*)&Wst[k * 128 + tx * 8];
                float4 t1 = *(const float4*)&Wst[k * 128 + tx * 8 + 4];
                float sv[8] = {s0.x, s0.y, s0.z, s0.w, s1.x, s1.y, s1.z, s1.w};
                float tv[8] = {t0.x, t0.y, t0.z, t0.w, t1.x, t1.y, t1.z, t1.w};
#pragma unroll
                for (int r = 0; r < 4; ++r)
#pragma unroll
                    for (int j = 0; j < 8; ++j) {
                        accs[r][j] += xr[r] * sv[j];
                        acct[r][j] += xr[r] * tv[j];
                    }
            }
        }
    }

    float bs[8], bt[8];
#pragma unroll
    for (int j = 0; j < 8; ++j) {
        bs[j] = bsig[tx * 8 + j];
        bt[j] = btanh[tx * 8 + j];
    }
    __syncthreads();
#pragma unroll
    for (int r = 0; r < 4; ++r) {
#pragma unroll
        for (int j = 0; j < 8; ++j) {
            float s = accs[r][j] + bs[j];
            s = fminf(fmaxf(s, -30.f), 30.f);
            float t = tanhf(acct[r][j] + bt[j]);
            float g = t / (1.f + expf(s));     // sigmoid(-s) * tanh(t)
            gs[(ty * 4 + r) * 128 + tx * 8 + j] = g;
        }
    }
    if (tid < BM) {
        int row = i0 + tid;
        bS[tid] = (row < n) ? batch[row] : -1;
    }
    __syncthreads();

    // run-length compressed pooling: batch is sorted, so per block only a few
    // distinct graph ids -> few atomics.
    int j = tid & 127;
    int m0 = (tid >> 7) * 32;
    float acc = 0.f;
    int cur = -1;
    for (int m = m0; m < m0 + 32; ++m) {
        int b = bS[m];
        if (b < 0) break;
        if (b != cur) {
            if (cur >= 0) atomicAdd(&pooled[(size_t)cur * 128 + j], acc);
            cur = b;
            acc = 0.f;
        }
        acc += gs[m * 128 + j];
    }
    if (cur >= 0) atomicAdd(&pooled[(size_t)cur * 128 + j], acc);
}

// ---------------------------------------------------------------------------
// Final per-graph MLP: f1 = leaky(p@Wf1+bf1); f2 = leaky(f1@Wf2+bf2);
// out = sigmoid(f2@Wout + bout). One block per graph.
// ---------------------------------------------------------------------------
__global__ __launch_bounds__(256) void mlp_kernel(
    const float* __restrict__ pooled,
    const float* __restrict__ Wf1, const float* __restrict__ bf1,
    const float* __restrict__ Wf2, const float* __restrict__ bf2,
    const float* __restrict__ Wout, const float* __restrict__ bout,
    float* __restrict__ out)
{
    __shared__ float p[128];
    __shared__ float f1[128];
    __shared__ float f2[258];
    __shared__ float red[4];

    int g = blockIdx.x;
    int tid = threadIdx.x;

    if (tid < 128) p[tid] = pooled[(size_t)g * 128 + tid];
    __syncthreads();

    if (tid < 128) {
        float a = bf1[tid];
        for (int k = 0; k < 128; ++k) a += p[k] * Wf1[k * 128 + tid];
        f1[tid] = LEAKY(a);
    }
    __syncthreads();

    for (int j = tid; j < 258; j += 256) {
        float a = bf2[j];
        for (int k = 0; k < 128; ++k) a += f1[k] * Wf2[k * 258 + j];
        f2[j] = LEAKY(a);
    }
    __syncthreads();

    float a = 0.f;
    for (int j = tid; j < 258; j += 256) a += f2[j] * Wout[j];
#pragma unroll
    for (int off = 32; off > 0; off >>= 1) a += __shfl_down(a, off, 64);
    if ((tid & 63) == 0) red[tid >> 6] = a;
    __syncthreads();
    if (tid == 0) {
        float v = red[0] + red[1] + red[2] + red[3] + bout[0];
        out[g] = 1.f / (1.f + expf(-v));
    }
}

// ---------------------------------------------------------------------------
extern "C" void kernel_launch(void* const* d_in, const int* in_sizes, int n_in,
                              void* d_out, int out_size, void* d_ws, size_t ws_size,
                              hipStream_t stream)
{
    const float* x     = (const float*)d_in[0];
    const int*   ei    = (const int*)d_in[1];
    const int*   batch = (const int*)d_in[2];
    const float* ea    = (const float*)d_in[3];
    const float* Wrel1 = (const float*)d_in[4];
    const float* brel1 = (const float*)d_in[5];
    const float* Wroot1= (const float*)d_in[6];
    const float* Wrel2 = (const float*)d_in[7];
    const float* brel2 = (const float*)d_in[8];
    const float* Wroot2= (const float*)d_in[9];
    const float* Wsig  = (const float*)d_in[10];
    const float* bsig  = (const float*)d_in[11];
    const float* Wtanh = (const float*)d_in[12];
    const float* btanh = (const float*)d_in[13];
    const float* Wf1   = (const float*)d_in[14];
    const float* bf1   = (const float*)d_in[15];
    const float* Wf2   = (const float*)d_in[16];
    const float* bf2   = (const float*)d_in[17];
    const float* Wout  = (const float*)d_in[18];
    const float* bout  = (const float*)d_in[19];

    int N = in_sizes[2];     // batch vector length = n_nodes
    int E = in_sizes[3];     // edge_attr length = n_edges

    float* ws = (float*)d_ws;
    float* R0 = ws;                              // agg1 (N*64), later h2 (N*128)
    float* R1 = ws + (size_t)N * 128;            // h1 (N*128)
    float* R2 = R1 + (size_t)N * 128;            // agg2 (N*128)
    float* R3 = R2 + (size_t)N * 128;            // pooled (256*128)

    float* agg1   = R0;
    float* h2     = R0;
    float* h1     = R1;
    float* agg2   = R2;
    float* pooled = R3;

    hipMemsetAsync(agg1, 0, (size_t)N * 64 * sizeof(float), stream);
    hipMemsetAsync(agg2, 0, (size_t)N * 128 * sizeof(float), stream);
    hipMemsetAsync(pooled, 0, (size_t)256 * 128 * sizeof(float), stream);

    // conv1: agg1 = scatter(x * w); h1 = leaky(agg1@Wrel1 + x@Wroot1 + brel1)
    {
        long long total = (long long)E * 64;
        int blocks = (int)((total + 255) / 256);
        scatter64_kernel<<<blocks, 256, 0, stream>>>(x, ei, ea, agg1, E);
    }
    {
        int blocks = (N + BM - 1) / BM;
        dual_linear_kernel<<<blocks, 256, 0, stream>>>(agg1, Wrel1, 64, x, Wroot1, 64,
                                                       brel1, h1, N);
    }
    // conv2
    {
        long long total = (long long)E * 128;
        int blocks = (int)((total + 255) / 256);
        scatter128_kernel<<<blocks, 256, 0, stream>>>(h1, ei, ea, agg2, E);
    }
    {
        int blocks = (N + BM - 1) / BM;
        dual_linear_kernel<<<blocks, 256, 0, stream>>>(agg2, Wrel2, 128, h1, Wroot2, 128,
                                                       brel2, h2, N);
    }
    // gate + pooled
    {
        int blocks = (N + BM - 1) / BM;
        gate_pool_kernel<<<blocks, 256, 0, stream>>>(h2, x, Wsig, bsig, Wtanh, btanh,
                                                     batch, pooled, N);
    }
    // final MLP
    mlp_kernel<<<256, 256, 0, stream>>>(pooled, Wf1, bf1, Wf2, bf2, Wout, bout,
                                        (float*)d_out);
}

// Round 2
// 838.150 us; speedup vs baseline: 1.7124x; 1.7124x over previous
//
#include <hip/hip_runtime.h>
#include <cstdint>

#define RELU_COEF 0.05f
#define LEAKY(v) ((v) > 0.f ? (v) : RELU_COEF * (v))

typedef __attribute__((ext_vector_type(8))) short short8;
typedef __attribute__((ext_vector_type(4))) float f32x4;

__device__ inline ushort f2bf(float f) {
    union { float f; uint32_t u; } v; v.f = f;
    return (ushort)((v.u + 0x7FFFu + ((v.u >> 16) & 1u)) >> 16);
}
__device__ inline float bf2f(ushort h) {
    union { uint32_t u; float f; } v; v.u = ((uint32_t)h) << 16;
    return v.f;
}

// ---------------------------------------------------------------------------
// CSR build: histogram -> exclusive scan -> fill
// ---------------------------------------------------------------------------
__global__ __launch_bounds__(256) void hist_kernel(
    const int* __restrict__ ei, int* __restrict__ deg, int E)
{
    int e = blockIdx.x * 256 + threadIdx.x;
    if (e >= E) return;
    atomicAdd(&deg[ei[(size_t)E + e]], 1);
}

__global__ __launch_bounds__(256) void scan1_kernel(
    const int* __restrict__ in, int* __restrict__ out, int* __restrict__ bsum, int N)
{
    __shared__ int ts[256];
    int tid = threadIdx.x;
    int base = blockIdx.x * 1024 + tid * 4;
    int v[4];
    int s = 0;
#pragma unroll
    for (int j = 0; j < 4; ++j) {
        int idx = base + j;
        v[j] = (idx < N) ? in[idx] : 0;
        s += v[j];
    }
    ts[tid] = s;
    __syncthreads();
    for (int off = 1; off < 256; off <<= 1) {
        int t = (tid >= off) ? ts[tid - off] : 0;
        __syncthreads();
        ts[tid] += t;
        __syncthreads();
    }
    int excl = ts[tid] - s;
    if (tid == 255) bsum[blockIdx.x] = ts[255];
    int run = excl;
#pragma unroll
    for (int j = 0; j < 4; ++j) {
        int idx = base + j;
        if (idx < N) out[idx] = run;
        run += v[j];
    }
}

__global__ __launch_bounds__(512) void scan2_kernel(int* bsum, int nb)
{
    __shared__ int ts[512];
    int tid = threadIdx.x;
    int v = (tid < nb) ? bsum[tid] : 0;
    ts[tid] = v;
    __syncthreads();
    for (int off = 1; off < 512; off <<= 1) {
        int t = (tid >= off) ? ts[tid - off] : 0;
        __syncthreads();
        ts[tid] += t;
        __syncthreads();
    }
    if (tid < nb) bsum[tid] = ts[tid] - v;   // exclusive
}

__global__ __launch_bounds__(256) void scan3_kernel(
    int* __restrict__ rowptr, const int* __restrict__ bsum, int N, int E)
{
    int idx = blockIdx.x * 256 + threadIdx.x;
    if (idx < N) rowptr[idx] += bsum[idx >> 10];
    if (idx == 0) rowptr[N] = E;
}

__global__ __launch_bounds__(256) void fill_kernel(
    const int* __restrict__ ei, const float* __restrict__ ea,
    int* __restrict__ cursor, int* __restrict__ csrc, float* __restrict__ cw, int E)
{
    int e = blockIdx.x * 256 + threadIdx.x;
    if (e >= E) return;
    int t = ei[(size_t)E + e];
    int pos = atomicAdd(&cursor[t], 1);
    csrc[pos] = ei[e];
    cw[pos] = ea[e];
}

// ---------------------------------------------------------------------------
// Gather aggregation: agg[i,d] = sum_{e in row i} w_e * feat[src_e, d]
// ---------------------------------------------------------------------------
template <int D>
__global__ __launch_bounds__(256) void gather_kernel(
    const float* __restrict__ feat, const int* __restrict__ rowptr,
    const int* __restrict__ csrc, const float* __restrict__ cw,
    float* __restrict__ agg, int N)
{
    const int per_block = 256 / D;
    int node = blockIdx.x * per_block + threadIdx.x / D;
    int d = threadIdx.x & (D - 1);
    if (node >= N) return;
    int b = rowptr[node];
    int e = rowptr[node + 1];
    float acc = 0.f;
    int k = b;
    for (; k + 1 < e; k += 2) {
        int s0 = csrc[k], s1 = csrc[k + 1];
        float w0 = cw[k], w1 = cw[k + 1];
        float f0 = feat[(size_t)s0 * D + d];
        float f1 = feat[(size_t)s1 * D + d];
        acc += w0 * f0;
        acc += w1 * f1;
    }
    if (k < e) acc += cw[k] * feat[(size_t)csrc[k] * D + d];
    agg[(size_t)node * D + d] = acc;
}

// ---------------------------------------------------------------------------
// Weight prep: transpose + split fp32 -> (hi,lo) bf16, k-contiguous layouts.
// Wt1 [n=128][2][K=128]  rows: k<64 Wrel1, else Wroot1
// Wt2 [n=128][2][K=256]  rows: k<128 Wrel2, else Wroot2
// Wtg [n=128][4][K=192]  slots: sigH, sigL, tanH, tanL (k<128 for h2, else x)
// ---------------------------------------------------------------------------
__global__ __launch_bounds__(256) void prep_weights_kernel(
    const float* __restrict__ Wrel1, const float* __restrict__ Wroot1,
    const float* __restrict__ Wrel2, const float* __restrict__ Wroot2,
    const float* __restrict__ Wsig, const float* __restrict__ Wtanh,
    ushort* __restrict__ Wt1, ushort* __restrict__ Wt2, ushort* __restrict__ Wtg)
{
    int gid = blockIdx.x * 256 + threadIdx.x;
    if (gid < 128 * 128) {
        int n = gid >> 7, k = gid & 127;
        float v = (k < 64) ? Wrel1[(size_t)k * 128 + n]
                           : Wroot1[(size_t)(k - 64) * 128 + n];
        ushort h = f2bf(v);
        Wt1[(size_t)n * 256 + k]       = h;
        Wt1[(size_t)n * 256 + 128 + k] = f2bf(v - bf2f(h));
        return;
    }
    int g2 = gid - 128 * 128;
    if (g2 < 128 * 256) {
        int n = g2 >> 8, k = g2 & 255;
        float v = (k < 128) ? Wrel2[(size_t)k * 128 + n]
                            : Wroot2[(size_t)(k - 128) * 128 + n];
        ushort h = f2bf(v);
        Wt2[(size_t)n * 512 + k]       = h;
        Wt2[(size_t)n * 512 + 256 + k] = f2bf(v - bf2f(h));
        return;
    }
    int g3 = g2 - 128 * 256;
    if (g3 < 128 * 192) {
        int n = g3 / 192, k = g3 % 192;
        float vs = Wsig[(size_t)k * 128 + n];
        float vt = Wtanh[(size_t)k * 128 + n];
        ushort hs = f2bf(vs), ht = f2bf(vt);
        Wtg[(size_t)n * 768 + k]       = hs;
        Wtg[(size_t)n * 768 + 192 + k] = f2bf(vs - bf2f(hs));
        Wtg[(size_t)n * 768 + 384 + k] = ht;
        Wtg[(size_t)n * 768 + 576 + k] = f2bf(vt - bf2f(ht));
    }
}

// ---------------------------------------------------------------------------
// MFMA split-bf16 dual linear: Y = leaky([A1|A2] @ Wcat + bias)
// Block = 64 rows x 128 cols, 4 waves (16 rows each). 16x16x32 bf16 MFMA,
// fp32 emulated via aH*bH + aH*bL + aL*bH.
// ---------------------------------------------------------------------------
template <int K1, int K2>
__global__ __launch_bounds__(256) void mfma_dual_kernel(
    const float* __restrict__ A1, const float* __restrict__ A2,
    const ushort* __restrict__ Wt, const float* __restrict__ bias,
    float* __restrict__ Y, int n)
{
    constexpr int K = K1 + K2;
    __shared__ ushort AsH[64 * 40];
    __shared__ ushort AsL[64 * 40];

    int tid = threadIdx.x;
    int lane = tid & 63;
    int w = tid >> 6;
    int mr = lane & 15;
    int kc = lane >> 4;
    int i0 = blockIdx.x * 64;

    const ushort* wp[8];
#pragma unroll
    for (int t = 0; t < 8; ++t)
        wp[t] = Wt + (size_t)(t * 16 + mr) * (2 * K) + kc * 8;

    const int aoff = (w * 16 + mr) * 40 + kc * 8;

    f32x4 acc[8] = {};

#pragma unroll
    for (int kk = 0; kk < K; kk += 32) {
        __syncthreads();
        {
            const float* src = (kk < K1) ? A1 : A2;
            const int Ks   = (kk < K1) ? K1 : K2;
            const int kloc = (kk < K1) ? kk : kk - K1;
#pragma unroll
            for (int l = 0; l < 2; ++l) {
                int idx = tid + l * 256;
                int m = idx >> 3, q = idx & 7;
                int row = i0 + m; if (row > n - 1) row = n - 1;
                float4 v = *(const float4*)(src + (size_t)row * Ks + kloc + q * 4);
                ushort4 h, lo;
                h.x = f2bf(v.x); lo.x = f2bf(v.x - bf2f(h.x));
                h.y = f2bf(v.y); lo.y = f2bf(v.y - bf2f(h.y));
                h.z = f2bf(v.z); lo.z = f2bf(v.z - bf2f(h.z));
                h.w = f2bf(v.w); lo.w = f2bf(v.w - bf2f(h.w));
                *(ushort4*)&AsH[m * 40 + q * 4] = h;
                *(ushort4*)&AsL[m * 40 + q * 4] = lo;
            }
        }
        __syncthreads();
        short8 aH = *(const short8*)&AsH[aoff];
        short8 aL = *(const short8*)&AsL[aoff];
#pragma unroll
        for (int t = 0; t < 8; ++t) {
            short8 bH = *(const short8*)(wp[t] + kk);
            short8 bL = *(const short8*)(wp[t] + K + kk);
            acc[t] = __builtin_amdgcn_mfma_f32_16x16x32_bf16(aH, bH, acc[t], 0, 0, 0);
            acc[t] = __builtin_amdgcn_mfma_f32_16x16x32_bf16(aH, bL, acc[t], 0, 0, 0);
            acc[t] = __builtin_amdgcn_mfma_f32_16x16x32_bf16(aL, bH, acc[t], 0, 0, 0);
        }
    }

#pragma unroll
    for (int t = 0; t < 8; ++t) {
        float bv = bias[t * 16 + mr];
#pragma unroll
        for (int j = 0; j < 4; ++j) {
            int row = i0 + w * 16 + kc * 4 + j;
            if (row < n) {
                float v = acc[t][j] + bv;
                Y[(size_t)row * 128 + t * 16 + mr] = LEAKY(v);
            }
        }
    }
}

// ---------------------------------------------------------------------------
// Fused conv2 + gate + pooling:
//   h2 = leaky(agg2@Wrel2 + h1@Wroot2 + brel2)      (kept in LDS, never stored)
//   s = clip([h2|x]@Wsig + bsig); t = tanh([h2|x]@Wtanh + btanh)
//   g = sigmoid(-s)*t; pooled[batch[i]] += g[i]     (run-compressed atomics)
// ---------------------------------------------------------------------------
__global__ __launch_bounds__(256) void mfma_conv2_gate_kernel(
    const float* __restrict__ A1 /*agg2*/, const float* __restrict__ A2 /*h1*/,
    const ushort* __restrict__ Wt2, const float* __restrict__ brel,
    const float* __restrict__ X, const ushort* __restrict__ Wtg,
    const float* __restrict__ bsig, const float* __restrict__ btanh,
    const int* __restrict__ batch, float* __restrict__ pooled, int n)
{
    __shared__ ushort AsH[64 * 40];
    __shared__ ushort AsL[64 * 40];
    __shared__ float h2s[64 * 132];
    __shared__ int bS[64];

    int tid = threadIdx.x;
    int lane = tid & 63;
    int w = tid >> 6;
    int mr = lane & 15;
    int kc = lane >> 4;
    int i0 = blockIdx.x * 64;

    const int aoff = (w * 16 + mr) * 40 + kc * 8;

    // ---- GEMM1: h2 tile = leaky([agg2|h1] @ Wt2 + brel) ----
    {
        const ushort* wp[8];
#pragma unroll
        for (int t = 0; t < 8; ++t)
            wp[t] = Wt2 + (size_t)(t * 16 + mr) * 512 + kc * 8;

        f32x4 acc[8] = {};
#pragma unroll
        for (int kk = 0; kk < 256; kk += 32) {
            __syncthreads();
            {
                const float* src = (kk < 128) ? A1 : A2;
                const int kloc = (kk < 128) ? kk : kk - 128;
#pragma unroll
                for (int l = 0; l < 2; ++l) {
                    int idx = tid + l * 256;
                    int m = idx >> 3, q = idx & 7;
                    int row = i0 + m; if (row > n - 1) row = n - 1;
                    float4 v = *(const float4*)(src + (size_t)row * 128 + kloc + q * 4);
                    ushort4 h, lo;
                    h.x = f2bf(v.x); lo.x = f2bf(v.x - bf2f(h.x));
                    h.y = f2bf(v.y); lo.y = f2bf(v.y - bf2f(h.y));
                    h.z = f2bf(v.z); lo.z = f2bf(v.z - bf2f(h.z));
                    h.w = f2bf(v.w); lo.w = f2bf(v.w - bf2f(h.w));
                    *(ushort4*)&AsH[m * 40 + q * 4] = h;
                    *(ushort4*)&AsL[m * 40 + q * 4] = lo;
                }
            }
            __syncthreads();
            short8 aH = *(const short8*)&AsH[aoff];
            short8 aL = *(const short8*)&AsL[aoff];
#pragma unroll
            for (int t = 0; t < 8; ++t) {
                short8 bH = *(const short8*)(wp[t] + kk);
                short8 bL = *(const short8*)(wp[t] + 256 + kk);
                acc[t] = __builtin_amdgcn_mfma_f32_16x16x32_bf16(aH, bH, acc[t], 0, 0, 0);
                acc[t] = __builtin_amdgcn_mfma_f32_16x16x32_bf16(aH, bL, acc[t], 0, 0, 0);
                acc[t] = __builtin_amdgcn_mfma_f32_16x16x32_bf16(aL, bH, acc[t], 0, 0, 0);
            }
        }

#pragma unroll
        for (int t = 0; t < 8; ++t) {
            float bv = brel[t * 16 + mr];
#pragma unroll
            for (int j = 0; j < 4; ++j) {
                float v = acc[t][j] + bv;
                h2s[(w * 16 + kc * 4 + j) * 132 + t * 16 + mr] = LEAKY(v);
            }
        }
    }

    // ---- GEMM2: gate over [h2(LDS) | x] ----
    const ushort* wg[8];
#pragma unroll
    for (int t = 0; t < 8; ++t)
        wg[t] = Wtg + (size_t)(t * 16 + mr) * 768 + kc * 8;

    f32x4 as[8] = {}, at_[8] = {};
#pragma unroll
    for (int kk = 0; kk < 192; kk += 32) {
        __syncthreads();   // also covers h2s-write -> first-stage-read hazard
        if (kk < 128) {
#pragma unroll
            for (int l = 0; l < 2; ++l) {
                int idx = tid + l * 256;
                int m = idx >> 3, q = idx & 7;
                float4 v = *(const float4*)&h2s[m * 132 + kk + q * 4];
                ushort4 h, lo;
                h.x = f2bf(v.x); lo.x = f2bf(v.x - bf2f(h.x));
                h.y = f2bf(v.y); lo.y = f2bf(v.y - bf2f(h.y));
                h.z = f2bf(v.z); lo.z = f2bf(v.z - bf2f(h.z));
                h.w = f2bf(v.w); lo.w = f2bf(v.w - bf2f(h.w));
                *(ushort4*)&AsH[m * 40 + q * 4] = h;
                *(ushort4*)&AsL[m * 40 + q * 4] = lo;
            }
        } else {
#pragma unroll
            for (int l = 0; l < 2; ++l) {
                int idx = tid + l * 256;
                int m = idx >> 3, q = idx & 7;
                int row = i0 + m; if (row > n - 1) row = n - 1;
                float4 v = *(const float4*)(X + (size_t)row * 64 + (kk - 128) + q * 4);
                ushort4 h, lo;
                h.x = f2bf(v.x); lo.x = f2bf(v.x - bf2f(h.x));
                h.y = f2bf(v.y); lo.y = f2bf(v.y - bf2f(h.y));
                h.z = f2bf(v.z); lo.z = f2bf(v.z - bf2f(h.z));
                h.w = f2bf(v.w); lo.w = f2bf(v.w - bf2f(h.w));
                *(ushort4*)&AsH[m * 40 + q * 4] = h;
                *(ushort4*)&AsL[m * 40 + q * 4] = lo;
            }
        }
        __syncthreads();
        short8 aH = *(const short8*)&AsH[aoff];
        short8 aL = *(const short8*)&AsL[aoff];
#pragma unroll
        for (int t = 0; t < 8; ++t) {
            short8 bsH = *(const short8*)(wg[t] + kk);
            short8 bsL = *(const short8*)(wg[t] + 192 + kk);
            short8 btH = *(const short8*)(wg[t] + 384 + kk);
            short8 btL = *(const short8*)(wg[t] + 576 + kk);
            as[t]  = __builtin_amdgcn_mfma_f32_16x16x32_bf16(aH, bsH, as[t], 0, 0, 0);
            as[t]  = __builtin_amdgcn_mfma_f32_16x16x32_bf16(aH, bsL, as[t], 0, 0, 0);
            as[t]  = __builtin_amdgcn_mfma_f32_16x16x32_bf16(aL, bsH, as[t], 0, 0, 0);
            at_[t] = __builtin_amdgcn_mfma_f32_16x16x32_bf16(aH, btH, at_[t], 0, 0, 0);
            at_[t] = __builtin_amdgcn_mfma_f32_16x16x32_bf16(aH, btL, at_[t], 0, 0, 0);
            at_[t] = __builtin_amdgcn_mfma_f32_16x16x32_bf16(aL, btH, at_[t], 0, 0, 0);
        }
    }

    // ---- gate epilogue + pooling (gs reuses h2s storage, stride 128) ----
    float* gs = h2s;
#pragma unroll
    for (int t = 0; t < 8; ++t) {
        int col = t * 16 + mr;
        float bsv = bsig[col], btv = btanh[col];
#pragma unroll
        for (int j = 0; j < 4; ++j) {
            int rloc = w * 16 + kc * 4 + j;
            float s = as[t][j] + bsv;
            s = fminf(fmaxf(s, -30.f), 30.f);
            float tt = tanhf(at_[t][j] + btv);
            gs[rloc * 128 + col] = tt / (1.f + expf(s));
        }
    }
    if (tid < 64) {
        int row = i0 + tid;
        bS[tid] = (row < n) ? batch[row] : -1;
    }
    __syncthreads();

    int j = tid & 127;
    int m0 = (tid >> 7) * 32;
    float acc2 = 0.f;
    int cur = -1;
    for (int m = m0; m < m0 + 32; ++m) {
        int b = bS[m];
        if (b < 0) break;
        if (b != cur) {
            if (cur >= 0) atomicAdd(&pooled[(size_t)cur * 128 + j], acc2);
            cur = b;
            acc2 = 0.f;
        }
        acc2 += gs[m * 128 + j];
    }
    if (cur >= 0) atomicAdd(&pooled[(size_t)cur * 128 + j], acc2);
}

// ---------------------------------------------------------------------------
// Final per-graph MLP
// ---------------------------------------------------------------------------
__global__ __launch_bounds__(256) void mlp_kernel(
    const float* __restrict__ pooled,
    const float* __restrict__ Wf1, const float* __restrict__ bf1,
    const float* __restrict__ Wf2, const float* __restrict__ bf2,
    const float* __restrict__ Wout, const float* __restrict__ bout,
    float* __restrict__ out)
{
    __shared__ float p[128];
    __shared__ float f1[128];
    __shared__ float f2[258];
    __shared__ float red[4];

    int g = blockIdx.x;
    int tid = threadIdx.x;

    if (tid < 128) p[tid] = pooled[(size_t)g * 128 + tid];
    __syncthreads();

    if (tid < 128) {
        float a = bf1[tid];
        for (int k = 0; k < 128; ++k) a += p[k] * Wf1[k * 128 + tid];
        f1[tid] = LEAKY(a);
    }
    __syncthreads();

    for (int j = tid; j < 258; j += 256) {
        float a = bf2[j];
        for (int k = 0; k < 128; ++k) a += f1[k] * Wf2[k * 258 + j];
        f2[j] = LEAKY(a);
    }
    __syncthreads();

    float a = 0.f;
    for (int j = tid; j < 258; j += 256) a += f2[j] * Wout[j];
#pragma unroll
    for (int off = 32; off > 0; off >>= 1) a += __shfl_down(a, off, 64);
    if ((tid & 63) == 0) red[tid >> 6] = a;
    __syncthreads();
    if (tid == 0) {
        float v = red[0] + red[1] + red[2] + red[3] + bout[0];
        out[g] = 1.f / (1.f + expf(-v));
    }
}

// ---------------------------------------------------------------------------
extern "C" void kernel_launch(void* const* d_in, const int* in_sizes, int n_in,
                              void* d_out, int out_size, void* d_ws, size_t ws_size,
                              hipStream_t stream)
{
    const float* x     = (const float*)d_in[0];
    const int*   ei    = (const int*)d_in[1];
    const int*   batch = (const int*)d_in[2];
    const float* ea    = (const float*)d_in[3];
    const float* Wrel1 = (const float*)d_in[4];
    const float* brel1 = (const float*)d_in[5];
    const float* Wroot1= (const float*)d_in[6];
    const float* Wrel2 = (const float*)d_in[7];
    const float* brel2 = (const float*)d_in[8];
    const float* Wroot2= (const float*)d_in[9];
    const float* Wsig  = (const float*)d_in[10];
    const float* bsig  = (const float*)d_in[11];
    const float* Wtanh = (const float*)d_in[12];
    const float* btanh = (const float*)d_in[13];
    const float* Wf1   = (const float*)d_in[14];
    const float* bf1   = (const float*)d_in[15];
    const float* Wf2   = (const float*)d_in[16];
    const float* bf2   = (const float*)d_in[17];
    const float* Wout  = (const float*)d_in[18];
    const float* bout  = (const float*)d_in[19];

    int N = in_sizes[2];     // n_nodes
    int E = in_sizes[3];     // n_edges

    float* ws = (float*)d_ws;
    float* R0 = ws;                               // agg1 (N*64) | CSR+Wt in upper half
    float* h1     = ws + (size_t)N * 128;         // R1
    float* agg2   = h1 + (size_t)N * 128;         // R2
    float* pooled = agg2 + (size_t)N * 128;       // R3 (256*128)
    float* agg1   = R0;

    // CSR + split weights packed into upper half of R0 (25.6 MB region, ~14 MB used).
    int*    rowptr = (int*)(R0 + (size_t)N * 64);   // N+1
    int*    cursor = rowptr + (N + 1);              // N
    int*    bsum   = cursor + N;                    // <=512
    int*    csrc   = bsum + 512;                    // E
    float*  cw     = (float*)(csrc + E);            // E
    ushort* Wt1    = (ushort*)(cw + E);             // 128*256
    ushort* Wt2    = Wt1 + 128 * 256;               // 128*512
    ushort* Wtg    = Wt2 + 128 * 512;               // 128*768

    int eblk = (E + 255) / 256;
    int nblk1 = (N + 1023) / 1024;
    int gblk = (N + 63) / 64;

    hipMemsetAsync(cursor, 0, (size_t)N * sizeof(int), stream);
    hipMemsetAsync(pooled, 0, (size_t)256 * 128 * sizeof(float), stream);

    prep_weights_kernel<<<288, 256, 0, stream>>>(Wrel1, Wroot1, Wrel2, Wroot2,
                                                 Wsig, Wtanh, Wt1, Wt2, Wtg);

    // ---- CSR build ----
    hist_kernel<<<eblk, 256, 0, stream>>>(ei, cursor, E);
    scan1_kernel<<<nblk1, 256, 0, stream>>>(cursor, rowptr, bsum, N);
    scan2_kernel<<<1, 512, 0, stream>>>(bsum, nblk1);
    scan3_kernel<<<(N + 255) / 256, 256, 0, stream>>>(rowptr, bsum, N, E);
    hipMemcpyAsync(cursor, rowptr, (size_t)N * sizeof(int),
                   hipMemcpyDeviceToDevice, stream);
    fill_kernel<<<eblk, 256, 0, stream>>>(ei, ea, cursor, csrc, cw, E);

    // ---- conv1 ----
    gather_kernel<64><<<(N + 3) / 4, 256, 0, stream>>>(x, rowptr, csrc, cw, agg1, N);
    mfma_dual_kernel<64, 64><<<gblk, 256, 0, stream>>>(agg1, x, Wt1, brel1, h1, N);

    // ---- conv2 + gate + pool (fused) ----
    gather_kernel<128><<<(N + 1) / 2, 256, 0, stream>>>(h1, rowptr, csrc, cw, agg2, N);
    mfma_conv2_gate_kernel<<<gblk, 256, 0, stream>>>(agg2, h1, Wt2, brel2,
                                                     x, Wtg, bsig, btanh,
                                                     batch, pooled, N);

    // ---- final MLP ----
    mlp_kernel<<<256, 256, 0, stream>>>(pooled, Wf1, bf1, Wf2, bf2, Wout, bout,
                                        (float*)d_out);
}

// Round 3
// 726.767 us; speedup vs baseline: 1.9749x; 1.1533x over previous
//
#include <hip/hip_runtime.h>
#include <cstdint>

#define RELU_COEF 0.05f
#define LEAKY(v) ((v) > 0.f ? (v) : RELU_COEF * (v))

typedef __attribute__((ext_vector_type(8))) short short8;
typedef __attribute__((ext_vector_type(4))) float f32x4;

__device__ inline ushort f2bf(float f) {
    union { float f; uint32_t u; } v; v.f = f;
    return (ushort)((v.u + 0x7FFFu + ((v.u >> 16) & 1u)) >> 16);
}
__device__ inline float bf2f(ushort h) {
    union { uint32_t u; float f; } v; v.u = ((uint32_t)h) << 16;
    return v.f;
}
// packed split-bf16: hi in high 16 bits, lo in low 16 bits
__device__ inline uint32_t packsplit(float v) {
    ushort hi = f2bf(v);
    ushort lo = f2bf(v - bf2f(hi));
    return ((uint32_t)hi << 16) | (uint32_t)lo;
}
__device__ inline float unpackval(uint32_t v) {
    union { uint32_t u; float f; } a, b;
    a.u = v & 0xFFFF0000u;   // hi
    b.u = v << 16;           // lo
    return a.f + b.f;
}
// 8 consecutive fp32 -> hi/lo short8 fragments
__device__ inline void split8(const float* p, short8& h8, short8& l8) {
    float4 a = *(const float4*)p;
    float4 b = *(const float4*)(p + 4);
    float v[8] = {a.x, a.y, a.z, a.w, b.x, b.y, b.z, b.w};
    short8 hh, ll;
#pragma unroll
    for (int i = 0; i < 8; ++i) {
        ushort hi = f2bf(v[i]);
        hh[i] = (short)hi;
        ll[i] = (short)f2bf(v[i] - bf2f(hi));
    }
    h8 = hh; l8 = ll;
}
// 8 packed uint32 -> hi/lo short8 fragments
__device__ inline void unpack8(const uint32_t* p, short8& h8, short8& l8) {
    uint4 a = *(const uint4*)p;
    uint4 b = *(const uint4*)(p + 4);
    union { uint32_t u[4]; short8 s; } H, L;
    uint32_t v0, v1;
    v0 = a.x; v1 = a.y; H.u[0] = (v0 >> 16) | (v1 & 0xFFFF0000u); L.u[0] = (v0 & 0xFFFFu) | (v1 << 16);
    v0 = a.z; v1 = a.w; H.u[1] = (v0 >> 16) | (v1 & 0xFFFF0000u); L.u[1] = (v0 & 0xFFFFu) | (v1 << 16);
    v0 = b.x; v1 = b.y; H.u[2] = (v0 >> 16) | (v1 & 0xFFFF0000u); L.u[2] = (v0 & 0xFFFFu) | (v1 << 16);
    v0 = b.z; v1 = b.w; H.u[3] = (v0 >> 16) | (v1 & 0xFFFF0000u); L.u[3] = (v0 & 0xFFFFu) | (v1 << 16);
    h8 = H.s; l8 = L.s;
}

// ---------------------------------------------------------------------------
// CSR build: histogram -> exclusive scan -> fill
// ---------------------------------------------------------------------------
__global__ __launch_bounds__(256) void hist_kernel(
    const int* __restrict__ ei, int* __restrict__ deg, int E)
{
    int e = blockIdx.x * 256 + threadIdx.x;
    if (e >= E) return;
    atomicAdd(&deg[ei[(size_t)E + e]], 1);
}

__global__ __launch_bounds__(256) void scan1_kernel(
    const int* __restrict__ in, int* __restrict__ out, int* __restrict__ bsum, int N)
{
    __shared__ int ts[256];
    int tid = threadIdx.x;
    int base = blockIdx.x * 1024 + tid * 4;
    int v[4];
    int s = 0;
#pragma unroll
    for (int j = 0; j < 4; ++j) {
        int idx = base + j;
        v[j] = (idx < N) ? in[idx] : 0;
        s += v[j];
    }
    ts[tid] = s;
    __syncthreads();
    for (int off = 1; off < 256; off <<= 1) {
        int t = (tid >= off) ? ts[tid - off] : 0;
        __syncthreads();
        ts[tid] += t;
        __syncthreads();
    }
    int excl = ts[tid] - s;
    if (tid == 255) bsum[blockIdx.x] = ts[255];
    int run = excl;
#pragma unroll
    for (int j = 0; j < 4; ++j) {
        int idx = base + j;
        if (idx < N) out[idx] = run;
        run += v[j];
    }
}

__global__ __launch_bounds__(512) void scan2_kernel(int* bsum, int nb)
{
    __shared__ int ts[512];
    int tid = threadIdx.x;
    int v = (tid < nb) ? bsum[tid] : 0;
    ts[tid] = v;
    __syncthreads();
    for (int off = 1; off < 512; off <<= 1) {
        int t = (tid >= off) ? ts[tid - off] : 0;
        __syncthreads();
        ts[tid] += t;
        __syncthreads();
    }
    if (tid < nb) bsum[tid] = ts[tid] - v;   // exclusive
}

__global__ __launch_bounds__(256) void scan3_kernel(
    int* __restrict__ rowptr, const int* __restrict__ bsum, int N, int E)
{
    int idx = blockIdx.x * 256 + threadIdx.x;
    if (idx < N) rowptr[idx] += bsum[idx >> 10];
    if (idx == 0) rowptr[N] = E;
}

__global__ __launch_bounds__(256) void fill_kernel(
    const int* __restrict__ ei, const float* __restrict__ ea,
    int* __restrict__ cursor, int* __restrict__ csrc, float* __restrict__ cw, int E)
{
    int e = blockIdx.x * 256 + threadIdx.x;
    if (e >= E) return;
    int t = ei[(size_t)E + e];
    int pos = atomicAdd(&cursor[t], 1);
    csrc[pos] = ei[e];
    cw[pos] = ea[e];
}

// ---------------------------------------------------------------------------
// gather64: agg planes (split bf16) from fp32 x. 16 threads/node, 4 cols each.
// ---------------------------------------------------------------------------
__global__ __launch_bounds__(256) void gather64_kernel(
    const float* __restrict__ feat, const int* __restrict__ rowptr,
    const int* __restrict__ csrc, const float* __restrict__ cw,
    ushort* __restrict__ aggH, ushort* __restrict__ aggL, int N)
{
    int node = blockIdx.x * 16 + (threadIdx.x >> 4);
    int q = threadIdx.x & 15;
    if (node >= N) return;
    int b = rowptr[node], e = rowptr[node + 1];
    float4 acc = make_float4(0.f, 0.f, 0.f, 0.f);
    int k = b;
    for (; k + 1 < e; k += 2) {
        int s0 = csrc[k], s1 = csrc[k + 1];
        float w0 = cw[k], w1 = cw[k + 1];
        float4 f0 = *(const float4*)(feat + (size_t)s0 * 64 + q * 4);
        float4 f1 = *(const float4*)(feat + (size_t)s1 * 64 + q * 4);
        acc.x += w0 * f0.x; acc.y += w0 * f0.y; acc.z += w0 * f0.z; acc.w += w0 * f0.w;
        acc.x += w1 * f1.x; acc.y += w1 * f1.y; acc.z += w1 * f1.z; acc.w += w1 * f1.w;
    }
    if (k < e) {
        int s0 = csrc[k]; float w0 = cw[k];
        float4 f0 = *(const float4*)(feat + (size_t)s0 * 64 + q * 4);
        acc.x += w0 * f0.x; acc.y += w0 * f0.y; acc.z += w0 * f0.z; acc.w += w0 * f0.w;
    }
    ushort4 hh, ll;
    hh.x = f2bf(acc.x); ll.x = f2bf(acc.x - bf2f(hh.x));
    hh.y = f2bf(acc.y); ll.y = f2bf(acc.y - bf2f(hh.y));
    hh.z = f2bf(acc.z); ll.z = f2bf(acc.z - bf2f(hh.z));
    hh.w = f2bf(acc.w); ll.w = f2bf(acc.w - bf2f(hh.w));
    *(ushort4*)(aggH + (size_t)node * 64 + q * 4) = hh;
    *(ushort4*)(aggL + (size_t)node * 64 + q * 4) = ll;
}

// ---------------------------------------------------------------------------
// gather128: reads packed-split h1 (uint32 rows, 512B), writes agg2 planes.
// 32 threads/node, 4 cols each.
// ---------------------------------------------------------------------------
__global__ __launch_bounds__(256) void gather128_kernel(
    const uint32_t* __restrict__ h1, const int* __restrict__ rowptr,
    const int* __restrict__ csrc, const float* __restrict__ cw,
    ushort* __restrict__ aggH, ushort* __restrict__ aggL, int N)
{
    int node = blockIdx.x * 8 + (threadIdx.x >> 5);
    int q = threadIdx.x & 31;
    if (node >= N) return;
    int b = rowptr[node], e = rowptr[node + 1];
    float4 acc = make_float4(0.f, 0.f, 0.f, 0.f);
    int k = b;
    for (; k + 1 < e; k += 2) {
        int s0 = csrc[k], s1 = csrc[k + 1];
        float w0 = cw[k], w1 = cw[k + 1];
        uint4 v0 = *(const uint4*)(h1 + (size_t)s0 * 128 + q * 4);
        uint4 v1 = *(const uint4*)(h1 + (size_t)s1 * 128 + q * 4);
        acc.x += w0 * unpackval(v0.x); acc.y += w0 * unpackval(v0.y);
        acc.z += w0 * unpackval(v0.z); acc.w += w0 * unpackval(v0.w);
        acc.x += w1 * unpackval(v1.x); acc.y += w1 * unpackval(v1.y);
        acc.z += w1 * unpackval(v1.z); acc.w += w1 * unpackval(v1.w);
    }
    if (k < e) {
        int s0 = csrc[k]; float w0 = cw[k];
        uint4 v0 = *(const uint4*)(h1 + (size_t)s0 * 128 + q * 4);
        acc.x += w0 * unpackval(v0.x); acc.y += w0 * unpackval(v0.y);
        acc.z += w0 * unpackval(v0.z); acc.w += w0 * unpackval(v0.w);
    }
    ushort4 hh, ll;
    hh.x = f2bf(acc.x); ll.x = f2bf(acc.x - bf2f(hh.x));
    hh.y = f2bf(acc.y); ll.y = f2bf(acc.y - bf2f(hh.y));
    hh.z = f2bf(acc.z); ll.z = f2bf(acc.z - bf2f(hh.z));
    hh.w = f2bf(acc.w); ll.w = f2bf(acc.w - bf2f(hh.w));
    *(ushort4*)(aggH + (size_t)node * 128 + q * 4) = hh;
    *(ushort4*)(aggL + (size_t)node * 128 + q * 4) = ll;
}

// ---------------------------------------------------------------------------
// Weight prep (unchanged layouts):
// Wt1 [n=128][2][K=128], Wt2 [n=128][2][K=256], Wtg [n=128][4][K=192]
// ---------------------------------------------------------------------------
__global__ __launch_bounds__(256) void prep_weights_kernel(
    const float* __restrict__ Wrel1, const float* __restrict__ Wroot1,
    const float* __restrict__ Wrel2, const float* __restrict__ Wroot2,
    const float* __restrict__ Wsig, const float* __restrict__ Wtanh,
    ushort* __restrict__ Wt1, ushort* __restrict__ Wt2, ushort* __restrict__ Wtg)
{
    int gid = blockIdx.x * 256 + threadIdx.x;
    if (gid < 128 * 128) {
        int n = gid >> 7, k = gid & 127;
        float v = (k < 64) ? Wrel1[(size_t)k * 128 + n]
                           : Wroot1[(size_t)(k - 64) * 128 + n];
        ushort h = f2bf(v);
        Wt1[(size_t)n * 256 + k]       = h;
        Wt1[(size_t)n * 256 + 128 + k] = f2bf(v - bf2f(h));
        return;
    }
    int g2 = gid - 128 * 128;
    if (g2 < 128 * 256) {
        int n = g2 >> 8, k = g2 & 255;
        float v = (k < 128) ? Wrel2[(size_t)k * 128 + n]
                            : Wroot2[(size_t)(k - 128) * 128 + n];
        ushort h = f2bf(v);
        Wt2[(size_t)n * 512 + k]       = h;
        Wt2[(size_t)n * 512 + 256 + k] = f2bf(v - bf2f(h));
        return;
    }
    int g3 = g2 - 128 * 256;
    if (g3 < 128 * 192) {
        int n = g3 / 192, k = g3 % 192;
        float vs = Wsig[(size_t)k * 128 + n];
        float vt = Wtanh[(size_t)k * 128 + n];
        ushort hs = f2bf(vs), ht = f2bf(vt);
        Wtg[(size_t)n * 768 + k]       = hs;
        Wtg[(size_t)n * 768 + 192 + k] = f2bf(vs - bf2f(hs));
        Wtg[(size_t)n * 768 + 384 + k] = ht;
        Wtg[(size_t)n * 768 + 576 + k] = f2bf(vt - bf2f(ht));
    }
}

// ---------------------------------------------------------------------------
// conv1 (barrier-free): h1 = packsplit(leaky([agg1|x]@Wt1 + brel1))
// 4 waves/block, each wave 16 rows x 128 cols. A from global planes / fp32.
// ---------------------------------------------------------------------------
__global__ __launch_bounds__(256) void mfma_conv1_kernel(
    const ushort* __restrict__ aggH, const ushort* __restrict__ aggL,
    const float* __restrict__ x, const ushort* __restrict__ Wt1,
    const float* __restrict__ brel, uint32_t* __restrict__ h1, int n)
{
    int tid = threadIdx.x;
    int lane = tid & 63;
    int w = tid >> 6;
    int mr = lane & 15;
    int kc = lane >> 4;
    int i0 = blockIdx.x * 64;
    int row = i0 + w * 16 + mr;
    if (row > n - 1) row = n - 1;

    const ushort* wb = Wt1 + (size_t)mr * 256 + kc * 8;
    f32x4 acc[8] = {};

#pragma unroll
    for (int kk = 0; kk < 64; kk += 32) {
        short8 aH = *(const short8*)(aggH + (size_t)row * 64 + kk + kc * 8);
        short8 aL = *(const short8*)(aggL + (size_t)row * 64 + kk + kc * 8);
#pragma unroll
        for (int t = 0; t < 8; ++t) {
            const ushort* bp = wb + t * 4096 + kk;
            short8 bH = *(const short8*)bp;
            short8 bL = *(const short8*)(bp + 128);
            acc[t] = __builtin_amdgcn_mfma_f32_16x16x32_bf16(aH, bH, acc[t], 0, 0, 0);
            acc[t] = __builtin_amdgcn_mfma_f32_16x16x32_bf16(aH, bL, acc[t], 0, 0, 0);
            acc[t] = __builtin_amdgcn_mfma_f32_16x16x32_bf16(aL, bH, acc[t], 0, 0, 0);
        }
    }
#pragma unroll
    for (int kk = 64; kk < 128; kk += 32) {
        short8 aH, aL;
        split8(x + (size_t)row * 64 + (kk - 64) + kc * 8, aH, aL);
#pragma unroll
        for (int t = 0; t < 8; ++t) {
            const ushort* bp = wb + t * 4096 + kk;
            short8 bH = *(const short8*)bp;
            short8 bL = *(const short8*)(bp + 128);
            acc[t] = __builtin_amdgcn_mfma_f32_16x16x32_bf16(aH, bH, acc[t], 0, 0, 0);
            acc[t] = __builtin_amdgcn_mfma_f32_16x16x32_bf16(aH, bL, acc[t], 0, 0, 0);
            acc[t] = __builtin_amdgcn_mfma_f32_16x16x32_bf16(aL, bH, acc[t], 0, 0, 0);
        }
    }

#pragma unroll
    for (int t = 0; t < 8; ++t) {
        int c = t * 16 + mr;
        float bv = brel[c];
#pragma unroll
        for (int j = 0; j < 4; ++j) {
            int r = i0 + w * 16 + kc * 4 + j;
            if (r < n) {
                float v = acc[t][j] + bv;
                h1[(size_t)r * 128 + c] = packsplit(LEAKY(v));
            }
        }
    }
}

// ---------------------------------------------------------------------------
// Fused conv2+gate+pool, 3 barriers total:
//   phase1 (barrier-free): h2 = leaky([agg2|h1]@Wt2+brel) -> LDS planes
//   phase2 (barrier-free A-reads from LDS): s,t GEMM over [h2|x]
//   epilogue: g = sigmoid(-clip(s))*tanh(t); run-compressed pooling
// ---------------------------------------------------------------------------
__global__ __launch_bounds__(256, 4) void conv2_gate_kernel(
    const ushort* __restrict__ agg2H, const ushort* __restrict__ agg2L,
    const uint32_t* __restrict__ h1, const float* __restrict__ x,
    const ushort* __restrict__ Wt2, const float* __restrict__ brel,
    const ushort* __restrict__ Wtg, const float* __restrict__ bsig,
    const float* __restrict__ btanh, const int* __restrict__ batch,
    float* __restrict__ pooled, int n)
{
    __shared__ char smem[2 * 64 * 136 * 2];   // h2 planes (34816B); gs aliases (32768B)
    __shared__ int bS[64];
    ushort* h2H = (ushort*)smem;
    ushort* h2L = h2H + 64 * 136;
    float* gs = (float*)smem;

    int tid = threadIdx.x;
    int lane = tid & 63;
    int w = tid >> 6;
    int mr = lane & 15;
    int kc = lane >> 4;
    int i0 = blockIdx.x * 64;
    int row = i0 + w * 16 + mr;
    if (row > n - 1) row = n - 1;

    // ---- phase 1: conv2 ----
    {
        const ushort* wb = Wt2 + (size_t)mr * 512 + kc * 8;
        f32x4 acc[8] = {};
#pragma unroll
        for (int kk = 0; kk < 128; kk += 32) {
            short8 aH = *(const short8*)(agg2H + (size_t)row * 128 + kk + kc * 8);
            short8 aL = *(const short8*)(agg2L + (size_t)row * 128 + kk + kc * 8);
#pragma unroll
            for (int t = 0; t < 8; ++t) {
                const ushort* bp = wb + t * 8192 + kk;
                short8 bH = *(const short8*)bp;
                short8 bL = *(const short8*)(bp + 256);
                acc[t] = __builtin_amdgcn_mfma_f32_16x16x32_bf16(aH, bH, acc[t], 0, 0, 0);
                acc[t] = __builtin_amdgcn_mfma_f32_16x16x32_bf16(aH, bL, acc[t], 0, 0, 0);
                acc[t] = __builtin_amdgcn_mfma_f32_16x16x32_bf16(aL, bH, acc[t], 0, 0, 0);
            }
        }
#pragma unroll
        for (int kk = 128; kk < 256; kk += 32) {
            short8 aH, aL;
            unpack8(h1 + (size_t)row * 128 + (kk - 128) + kc * 8, aH, aL);
#pragma unroll
            for (int t = 0; t < 8; ++t) {
                const ushort* bp = wb + t * 8192 + kk;
                short8 bH = *(const short8*)bp;
                short8 bL = *(const short8*)(bp + 256);
                acc[t] = __builtin_amdgcn_mfma_f32_16x16x32_bf16(aH, bH, acc[t], 0, 0, 0);
                acc[t] = __builtin_amdgcn_mfma_f32_16x16x32_bf16(aH, bL, acc[t], 0, 0, 0);
                acc[t] = __builtin_amdgcn_mfma_f32_16x16x32_bf16(aL, bH, acc[t], 0, 0, 0);
            }
        }
#pragma unroll
        for (int t = 0; t < 8; ++t) {
            int c = t * 16 + mr;
            float bv = brel[c];
#pragma unroll
            for (int j = 0; j < 4; ++j) {
                int rl = w * 16 + kc * 4 + j;
                float v = LEAKY(acc[t][j] + bv);
                ushort hi = f2bf(v);
                h2H[rl * 136 + c] = hi;
                h2L[rl * 136 + c] = f2bf(v - bf2f(hi));
            }
        }
    }
    __syncthreads();

    // ---- phase 2: gate GEMM ----
    f32x4 as[8] = {}, at_[8] = {};
    {
        const ushort* wg = Wtg + (size_t)mr * 768 + kc * 8;
        const int arow = (w * 16 + mr) * 136;
#pragma unroll
        for (int kk = 0; kk < 128; kk += 32) {
            short8 aH = *(const short8*)(h2H + arow + kk + kc * 8);
            short8 aL = *(const short8*)(h2L + arow + kk + kc * 8);
#pragma unroll
            for (int t = 0; t < 8; ++t) {
                const ushort* bp = wg + t * 12288 + kk;
                short8 bsH = *(const short8*)bp;
                short8 bsL = *(const short8*)(bp + 192);
                short8 btH = *(const short8*)(bp + 384);
                short8 btL = *(const short8*)(bp + 576);
                as[t]  = __builtin_amdgcn_mfma_f32_16x16x32_bf16(aH, bsH, as[t], 0, 0, 0);
                as[t]  = __builtin_amdgcn_mfma_f32_16x16x32_bf16(aH, bsL, as[t], 0, 0, 0);
                as[t]  = __builtin_amdgcn_mfma_f32_16x16x32_bf16(aL, bsH, as[t], 0, 0, 0);
                at_[t] = __builtin_amdgcn_mfma_f32_16x16x32_bf16(aH, btH, at_[t], 0, 0, 0);
                at_[t] = __builtin_amdgcn_mfma_f32_16x16x32_bf16(aH, btL, at_[t], 0, 0, 0);
                at_[t] = __builtin_amdgcn_mfma_f32_16x16x32_bf16(aL, btH, at_[t], 0, 0, 0);
            }
        }
#pragma unroll
        for (int kk = 128; kk < 192; kk += 32) {
            short8 aH, aL;
            split8(x + (size_t)row * 64 + (kk - 128) + kc * 8, aH, aL);
#pragma unroll
            for (int t = 0; t < 8; ++t) {
                const ushort* bp = wg + t * 12288 + kk;
                short8 bsH = *(const short8*)bp;
                short8 bsL = *(const short8*)(bp + 192);
                short8 btH = *(const short8*)(bp + 384);
                short8 btL = *(const short8*)(bp + 576);
                as[t]  = __builtin_amdgcn_mfma_f32_16x16x32_bf16(aH, bsH, as[t], 0, 0, 0);
                as[t]  = __builtin_amdgcn_mfma_f32_16x16x32_bf16(aH, bsL, as[t], 0, 0, 0);
                as[t]  = __builtin_amdgcn_mfma_f32_16x16x32_bf16(aL, bsH, as[t], 0, 0, 0);
                at_[t] = __builtin_amdgcn_mfma_f32_16x16x32_bf16(aH, btH, at_[t], 0, 0, 0);
                at_[t] = __builtin_amdgcn_mfma_f32_16x16x32_bf16(aH, btL, at_[t], 0, 0, 0);
                at_[t] = __builtin_amdgcn_mfma_f32_16x16x32_bf16(aL, btH, at_[t], 0, 0, 0);
            }
        }
    }
    __syncthreads();   // all LDS h2 reads done -> safe to alias as gs

    // ---- gate epilogue ----
#pragma unroll
    for (int t = 0; t < 8; ++t) {
        int c = t * 16 + mr;
        float bsv = bsig[c], btv = btanh[c];
#pragma unroll
        for (int j = 0; j < 4; ++j) {
            int rl = w * 16 + kc * 4 + j;
            float s = as[t][j] + bsv;
            s = fminf(fmaxf(s, -30.f), 30.f);
            float ta = at_[t][j] + btv;
            ta = fminf(fmaxf(ta, -15.f), 15.f);
            float e2 = __expf(2.f * ta);
            float tt = (e2 - 1.f) / (e2 + 1.f);
            gs[rl * 128 + c] = tt / (1.f + __expf(s));
        }
    }
    if (tid < 64) {
        int r = i0 + tid;
        bS[tid] = (r < n) ? batch[r] : -1;
    }
    __syncthreads();

    // ---- run-compressed pooling ----
    int j = tid & 127;
    int m0 = (tid >> 7) * 32;
    float acc2 = 0.f;
    int cur = -1;
    for (int m = m0; m < m0 + 32; ++m) {
        int b = bS[m];
        if (b < 0) break;
        if (b != cur) {
            if (cur >= 0) atomicAdd(&pooled[(size_t)cur * 128 + j], acc2);
            cur = b;
            acc2 = 0.f;
        }
        acc2 += gs[m * 128 + j];
    }
    if (cur >= 0) atomicAdd(&pooled[(size_t)cur * 128 + j], acc2);
}

// ---------------------------------------------------------------------------
// Final per-graph MLP
// ---------------------------------------------------------------------------
__global__ __launch_bounds__(256) void mlp_kernel(
    const float* __restrict__ pooled,
    const float* __restrict__ Wf1, const float* __restrict__ bf1,
    const float* __restrict__ Wf2, const float* __restrict__ bf2,
    const float* __restrict__ Wout, const float* __restrict__ bout,
    float* __restrict__ out)
{
    __shared__ float p[128];
    __shared__ float f1[128];
    __shared__ float f2[258];
    __shared__ float red[4];

    int g = blockIdx.x;
    int tid = threadIdx.x;

    if (tid < 128) p[tid] = pooled[(size_t)g * 128 + tid];
    __syncthreads();

    if (tid < 128) {
        float a = bf1[tid];
        for (int k = 0; k < 128; ++k) a += p[k] * Wf1[k * 128 + tid];
        f1[tid] = LEAKY(a);
    }
    __syncthreads();

    for (int j = tid; j < 258; j += 256) {
        float a = bf2[j];
        for (int k = 0; k < 128; ++k) a += f1[k] * Wf2[k * 258 + j];
        f2[j] = LEAKY(a);
    }
    __syncthreads();

    float a = 0.f;
    for (int j = tid; j < 258; j += 256) a += f2[j] * Wout[j];
#pragma unroll
    for (int off = 32; off > 0; off >>= 1) a += __shfl_down(a, off, 64);
    if ((tid & 63) == 0) red[tid >> 6] = a;
    __syncthreads();
    if (tid == 0) {
        float v = red[0] + red[1] + red[2] + red[3] + bout[0];
        out[g] = 1.f / (1.f + expf(-v));
    }
}

// ---------------------------------------------------------------------------
extern "C" void kernel_launch(void* const* d_in, const int* in_sizes, int n_in,
                              void* d_out, int out_size, void* d_ws, size_t ws_size,
                              hipStream_t stream)
{
    const float* x     = (const float*)d_in[0];
    const int*   ei    = (const int*)d_in[1];
    const int*   batch = (const int*)d_in[2];
    const float* ea    = (const float*)d_in[3];
    const float* Wrel1 = (const float*)d_in[4];
    const float* brel1 = (const float*)d_in[5];
    const float* Wroot1= (const float*)d_in[6];
    const float* Wrel2 = (const float*)d_in[7];
    const float* brel2 = (const float*)d_in[8];
    const float* Wroot2= (const float*)d_in[9];
    const float* Wsig  = (const float*)d_in[10];
    const float* bsig  = (const float*)d_in[11];
    const float* Wtanh = (const float*)d_in[12];
    const float* btanh = (const float*)d_in[13];
    const float* Wf1   = (const float*)d_in[14];
    const float* bf1   = (const float*)d_in[15];
    const float* Wf2   = (const float*)d_in[16];
    const float* bf2   = (const float*)d_in[17];
    const float* Wout  = (const float*)d_in[18];
    const float* bout  = (const float*)d_in[19];

    int N = in_sizes[2];     // n_nodes
    int E = in_sizes[3];     // n_edges

    char* base = (char*)d_ws;
    size_t off = 0;
    auto alloc = [&](size_t bytes) {
        char* p = base + off;
        off += (bytes + 255) & ~(size_t)255;
        return p;
    };
    uint32_t* h1    = (uint32_t*)alloc((size_t)N * 128 * 4);
    ushort*   agg2H = (ushort*)alloc((size_t)N * 128 * 2);
    ushort*   agg2L = (ushort*)alloc((size_t)N * 128 * 2);
    ushort*   agg1H = (ushort*)alloc((size_t)N * 64 * 2);
    ushort*   agg1L = (ushort*)alloc((size_t)N * 64 * 2);
    int*      rowptr= (int*)alloc((size_t)(N + 1) * 4);
    int*      cursor= (int*)alloc((size_t)N * 4);
    int*      bsum  = (int*)alloc(512 * 4);
    int*      csrc  = (int*)alloc((size_t)E * 4);
    float*    cwgt  = (float*)alloc((size_t)E * 4);
    ushort*   Wt1   = (ushort*)alloc(128 * 256 * 2);
    ushort*   Wt2   = (ushort*)alloc(128 * 512 * 2);
    ushort*   Wtg   = (ushort*)alloc(128 * 768 * 2);
    float*    pooled= (float*)alloc(256 * 128 * 4);

    int eblk = (E + 255) / 256;
    int nblk1 = (N + 1023) / 1024;
    int cblk = (N + 63) / 64;

    hipMemsetAsync(cursor, 0, (size_t)N * sizeof(int), stream);
    hipMemsetAsync(pooled, 0, (size_t)256 * 128 * sizeof(float), stream);

    prep_weights_kernel<<<288, 256, 0, stream>>>(Wrel1, Wroot1, Wrel2, Wroot2,
                                                 Wsig, Wtanh, Wt1, Wt2, Wtg);

    // ---- CSR build ----
    hist_kernel<<<eblk, 256, 0, stream>>>(ei, cursor, E);
    scan1_kernel<<<nblk1, 256, 0, stream>>>(cursor, rowptr, bsum, N);
    scan2_kernel<<<1, 512, 0, stream>>>(bsum, nblk1);
    scan3_kernel<<<(N + 255) / 256, 256, 0, stream>>>(rowptr, bsum, N, E);
    hipMemcpyAsync(cursor, rowptr, (size_t)N * sizeof(int),
                   hipMemcpyDeviceToDevice, stream);
    fill_kernel<<<eblk, 256, 0, stream>>>(ei, ea, cursor, csrc, cwgt, E);

    // ---- conv1 ----
    gather64_kernel<<<(N + 15) / 16, 256, 0, stream>>>(x, rowptr, csrc, cwgt,
                                                       agg1H, agg1L, N);
    mfma_conv1_kernel<<<cblk, 256, 0, stream>>>(agg1H, agg1L, x, Wt1, brel1, h1, N);

    // ---- conv2 + gate + pool ----
    gather128_kernel<<<(N + 7) / 8, 256, 0, stream>>>(h1, rowptr, csrc, cwgt,
                                                      agg2H, agg2L, N);
    conv2_gate_kernel<<<cblk, 256, 0, stream>>>(agg2H, agg2L, h1, x, Wt2, brel2,
                                                Wtg, bsig, btanh, batch, pooled, N);

    // ---- final MLP ----
    mlp_kernel<<<256, 256, 0, stream>>>(pooled, Wf1, bf1, Wf2, bf2, Wout, bout,
                                        (float*)d_out);
}

// Round 4
// 646.537 us; speedup vs baseline: 2.2200x; 1.1241x over previous
//
#include <hip/hip_runtime.h>
#include <cstdint>

#define RELU_COEF 0.05f
#define LEAKY(v) ((v) > 0.f ? (v) : RELU_COEF * (v))

typedef __attribute__((ext_vector_type(8))) short short8;
typedef __attribute__((ext_vector_type(4))) float f32x4;

#define MFMA(acc, a, b) \
    acc = __builtin_amdgcn_mfma_f32_16x16x32_bf16(a, b, acc, 0, 0, 0)

__device__ inline ushort f2bf(float f) {
    union { float f; uint32_t u; } v; v.f = f;
    return (ushort)((v.u + 0x7FFFu + ((v.u >> 16) & 1u)) >> 16);
}
__device__ inline float bf2f(ushort h) {
    union { uint32_t u; float f; } v; v.u = ((uint32_t)h) << 16;
    return v.f;
}
__device__ inline uint32_t packsplit(float v) {
    ushort hi = f2bf(v);
    ushort lo = f2bf(v - bf2f(hi));
    return ((uint32_t)hi << 16) | (uint32_t)lo;
}
__device__ inline float unpackval(uint32_t v) {
    union { uint32_t u; float f; } a, b;
    a.u = v & 0xFFFF0000u;
    b.u = v << 16;
    return a.f + b.f;
}
__device__ inline void split8(const float* p, short8& h8, short8& l8) {
    float4 a = *(const float4*)p;
    float4 b = *(const float4*)(p + 4);
    float v[8] = {a.x, a.y, a.z, a.w, b.x, b.y, b.z, b.w};
    short8 hh, ll;
#pragma unroll
    for (int i = 0; i < 8; ++i) {
        ushort hi = f2bf(v[i]);
        hh[i] = (short)hi;
        ll[i] = (short)f2bf(v[i] - bf2f(hi));
    }
    h8 = hh; l8 = ll;
}
__device__ inline void unpack8(const uint32_t* p, short8& h8, short8& l8) {
    uint4 a = *(const uint4*)p;
    uint4 b = *(const uint4*)(p + 4);
    union { uint32_t u[4]; short8 s; } H, L;
    uint32_t v0, v1;
    v0 = a.x; v1 = a.y; H.u[0] = (v0 >> 16) | (v1 & 0xFFFF0000u); L.u[0] = (v0 & 0xFFFFu) | (v1 << 16);
    v0 = a.z; v1 = a.w; H.u[1] = (v0 >> 16) | (v1 & 0xFFFF0000u); L.u[1] = (v0 & 0xFFFFu) | (v1 << 16);
    v0 = b.x; v1 = b.y; H.u[2] = (v0 >> 16) | (v1 & 0xFFFF0000u); L.u[2] = (v0 & 0xFFFFu) | (v1 << 16);
    v0 = b.z; v1 = b.w; H.u[3] = (v0 >> 16) | (v1 & 0xFFFF0000u); L.u[3] = (v0 & 0xFFFFu) | (v1 << 16);
    h8 = H.s; l8 = L.s;
}

// ---------------------------------------------------------------------------
// CSR build
// ---------------------------------------------------------------------------
__global__ __launch_bounds__(256) void hist_kernel(
    const int* __restrict__ ei, int* __restrict__ deg, int E)
{
    int e = blockIdx.x * 256 + threadIdx.x;
    if (e >= E) return;
    atomicAdd(&deg[ei[(size_t)E + e]], 1);
}

__global__ __launch_bounds__(256) void scan1_kernel(
    const int* __restrict__ in, int* __restrict__ out, int* __restrict__ bsum, int N)
{
    __shared__ int ts[256];
    int tid = threadIdx.x;
    int base = blockIdx.x * 1024 + tid * 4;
    int v[4];
    int s = 0;
#pragma unroll
    for (int j = 0; j < 4; ++j) {
        int idx = base + j;
        v[j] = (idx < N) ? in[idx] : 0;
        s += v[j];
    }
    ts[tid] = s;
    __syncthreads();
    for (int off = 1; off < 256; off <<= 1) {
        int t = (tid >= off) ? ts[tid - off] : 0;
        __syncthreads();
        ts[tid] += t;
        __syncthreads();
    }
    int excl = ts[tid] - s;
    if (tid == 255) bsum[blockIdx.x] = ts[255];
    int run = excl;
#pragma unroll
    for (int j = 0; j < 4; ++j) {
        int idx = base + j;
        if (idx < N) out[idx] = run;
        run += v[j];
    }
}

__global__ __launch_bounds__(512) void scan2_kernel(int* bsum, int nb)
{
    __shared__ int ts[512];
    int tid = threadIdx.x;
    int v = (tid < nb) ? bsum[tid] : 0;
    ts[tid] = v;
    __syncthreads();
    for (int off = 1; off < 512; off <<= 1) {
        int t = (tid >= off) ? ts[tid - off] : 0;
        __syncthreads();
        ts[tid] += t;
        __syncthreads();
    }
    if (tid < nb) bsum[tid] = ts[tid] - v;
}

__global__ __launch_bounds__(256) void scan3_kernel(
    int* __restrict__ rowptr, const int* __restrict__ bsum, int N, int E)
{
    int idx = blockIdx.x * 256 + threadIdx.x;
    if (idx < N) rowptr[idx] += bsum[idx >> 10];
    if (idx == 0) rowptr[N] = E;
}

__global__ __launch_bounds__(256) void fill_kernel(
    const int* __restrict__ ei, const float* __restrict__ ea,
    int* __restrict__ cursor, int* __restrict__ csrc, float* __restrict__ cw, int E)
{
    int e = blockIdx.x * 256 + threadIdx.x;
    if (e >= E) return;
    int t = ei[(size_t)E + e];
    int pos = atomicAdd(&cursor[t], 1);
    csrc[pos] = ei[e];
    cw[pos] = ea[e];
}

// ---------------------------------------------------------------------------
// Weight prep -> fragment-major split-bf16 layouts (coalesced B loads):
// W1f[kk:4][hl:2][kc:4][n:128][e:8]   (K=128: agg1|x)
// W2f[kk:8][hl:2][kc:4][n:128][e:8]   (K=256: agg2|h1)
// Wgf[kk:6][p:4 (sH,sL,tH,tL)][kc:4][n:128][e:8]  (K=192: h2|x)
// ---------------------------------------------------------------------------
__global__ __launch_bounds__(256) void prep_weights_kernel(
    const float* __restrict__ Wrel1, const float* __restrict__ Wroot1,
    const float* __restrict__ Wrel2, const float* __restrict__ Wroot2,
    const float* __restrict__ Wsig, const float* __restrict__ Wtanh,
    ushort* __restrict__ W1f, ushort* __restrict__ W2f, ushort* __restrict__ Wgf)
{
    int gid = blockIdx.x * 256 + threadIdx.x;
    if (gid < 32768) {
        int e = gid & 7, nn = (gid >> 3) & 127, kc = (gid >> 10) & 3;
        int hl = (gid >> 12) & 1, kk = gid >> 13;
        int k = kk * 32 + kc * 8 + e;
        float v = (k < 64) ? Wrel1[(size_t)k * 128 + nn]
                           : Wroot1[(size_t)(k - 64) * 128 + nn];
        ushort hi = f2bf(v);
        W1f[gid] = hl ? f2bf(v - bf2f(hi)) : hi;
        return;
    }
    int g2 = gid - 32768;
    if (g2 < 65536) {
        int e = g2 & 7, nn = (g2 >> 3) & 127, kc = (g2 >> 10) & 3;
        int hl = (g2 >> 12) & 1, kk = g2 >> 13;
        int k = kk * 32 + kc * 8 + e;
        float v = (k < 128) ? Wrel2[(size_t)k * 128 + nn]
                            : Wroot2[(size_t)(k - 128) * 128 + nn];
        ushort hi = f2bf(v);
        W2f[g2] = hl ? f2bf(v - bf2f(hi)) : hi;
        return;
    }
    int g3 = g2 - 65536;
    if (g3 < 98304) {
        int e = g3 & 7, nn = (g3 >> 3) & 127, kc = (g3 >> 10) & 3;
        int p = (g3 >> 12) & 3, kk = g3 >> 14;
        int k = kk * 32 + kc * 8 + e;
        float v = (p < 2) ? Wsig[(size_t)k * 128 + nn]
                          : Wtanh[(size_t)k * 128 + nn];
        ushort hi = f2bf(v);
        Wgf[g3] = (p & 1) ? f2bf(v - bf2f(hi)) : hi;
    }
}

// ---------------------------------------------------------------------------
// Fused conv1: gather(x) -> LDS planes; h1 = packsplit(leaky([agg1|x]@W1 + b))
// 4 waves; wave w owns output cols [2w*16, 2w*16+32) for all 64 rows.
// ---------------------------------------------------------------------------
__global__ __launch_bounds__(256) void conv1_fused_kernel(
    const float* __restrict__ x, const int* __restrict__ rowptr,
    const int* __restrict__ csrc, const float* __restrict__ cw,
    const ushort* __restrict__ W1f, const float* __restrict__ brel,
    uint32_t* __restrict__ h1, int n)
{
    __shared__ __align__(16) ushort AH[64 * 72];
    __shared__ __align__(16) ushort AL[64 * 72];

    int tid = threadIdx.x;
    int lane = tid & 63;
    int wv = tid >> 6;
    int mr = lane & 15;
    int kc = lane >> 4;          // 0..3
    int i0 = blockIdx.x * 64;

    // ---- gather phase: 16 lanes/node, 16 nodes in parallel, 4 iters ----
    {
        int q = tid & 15;
        int g = tid >> 4;
#pragma unroll
        for (int it = 0; it < 4; ++it) {
            int rl = it * 16 + g;
            int node = i0 + rl;
            float4 a = make_float4(0.f, 0.f, 0.f, 0.f);
            if (node < n) {
                int b = rowptr[node], e = rowptr[node + 1];
                int k = b;
                for (; k + 1 < e; k += 2) {
                    int s0 = csrc[k], s1 = csrc[k + 1];
                    float w0 = cw[k], w1 = cw[k + 1];
                    float4 f0 = *(const float4*)(x + (size_t)s0 * 64 + q * 4);
                    float4 f1 = *(const float4*)(x + (size_t)s1 * 64 + q * 4);
                    a.x += w0 * f0.x; a.y += w0 * f0.y; a.z += w0 * f0.z; a.w += w0 * f0.w;
                    a.x += w1 * f1.x; a.y += w1 * f1.y; a.z += w1 * f1.z; a.w += w1 * f1.w;
                }
                if (k < e) {
                    int s0 = csrc[k]; float w0 = cw[k];
                    float4 f0 = *(const float4*)(x + (size_t)s0 * 64 + q * 4);
                    a.x += w0 * f0.x; a.y += w0 * f0.y; a.z += w0 * f0.z; a.w += w0 * f0.w;
                }
            }
            ushort4 hh, ll;
            hh.x = f2bf(a.x); ll.x = f2bf(a.x - bf2f(hh.x));
            hh.y = f2bf(a.y); ll.y = f2bf(a.y - bf2f(hh.y));
            hh.z = f2bf(a.z); ll.z = f2bf(a.z - bf2f(hh.z));
            hh.w = f2bf(a.w); ll.w = f2bf(a.w - bf2f(hh.w));
            *(ushort4*)&AH[rl * 72 + q * 4] = hh;
            *(ushort4*)&AL[rl * 72 + q * 4] = ll;
        }
    }
    __syncthreads();

    // ---- GEMM ----
    int t0 = wv * 2;
    const ushort* Wp = W1f + kc * 1024 + t0 * 128 + mr * 8;
    f32x4 acc[4][2] = {};

#pragma unroll
    for (int kk = 0; kk < 2; ++kk) {      // A from LDS agg1 (K 0..63)
        short8 bH0 = *(const short8*)(Wp + kk * 8192);
        short8 bH1 = *(const short8*)(Wp + kk * 8192 + 128);
        short8 bL0 = *(const short8*)(Wp + kk * 8192 + 4096);
        short8 bL1 = *(const short8*)(Wp + kk * 8192 + 4096 + 128);
#pragma unroll
        for (int sub = 0; sub < 4; ++sub) {
            short8 aH = *(const short8*)&AH[(sub * 16 + mr) * 72 + kk * 32 + kc * 8];
            short8 aL = *(const short8*)&AL[(sub * 16 + mr) * 72 + kk * 32 + kc * 8];
            MFMA(acc[sub][0], aH, bH0); MFMA(acc[sub][0], aH, bL0); MFMA(acc[sub][0], aL, bH0);
            MFMA(acc[sub][1], aH, bH1); MFMA(acc[sub][1], aH, bL1); MFMA(acc[sub][1], aL, bH1);
        }
    }
#pragma unroll
    for (int kk = 2; kk < 4; ++kk) {      // A from x (K 64..127)
        short8 bH0 = *(const short8*)(Wp + kk * 8192);
        short8 bH1 = *(const short8*)(Wp + kk * 8192 + 128);
        short8 bL0 = *(const short8*)(Wp + kk * 8192 + 4096);
        short8 bL1 = *(const short8*)(Wp + kk * 8192 + 4096 + 128);
#pragma unroll
        for (int sub = 0; sub < 4; ++sub) {
            int row = i0 + sub * 16 + mr; if (row > n - 1) row = n - 1;
            short8 aH, aL;
            split8(x + (size_t)row * 64 + (kk - 2) * 32 + kc * 8, aH, aL);
            MFMA(acc[sub][0], aH, bH0); MFMA(acc[sub][0], aH, bL0); MFMA(acc[sub][0], aL, bH0);
            MFMA(acc[sub][1], aH, bH1); MFMA(acc[sub][1], aH, bL1); MFMA(acc[sub][1], aL, bH1);
        }
    }

#pragma unroll
    for (int tt = 0; tt < 2; ++tt) {
        int c = (t0 + tt) * 16 + mr;
        float bv = brel[c];
#pragma unroll
        for (int sub = 0; sub < 4; ++sub)
#pragma unroll
            for (int j = 0; j < 4; ++j) {
                int r = i0 + sub * 16 + kc * 4 + j;
                if (r < n)
                    h1[(size_t)r * 128 + c] = packsplit(LEAKY(acc[sub][tt][j] + bv));
            }
    }
}

// ---------------------------------------------------------------------------
// Fused conv2 + gate + pool:
//   gather(h1) -> LDS planes; h2 = leaky([agg2|h1]@W2+b) -> LDS (aliased);
//   s,t = [h2|x]@Wsig/Wtanh; g = sigmoid(-clip(s))*tanh(t); pool by batch.
// ---------------------------------------------------------------------------
__global__ __launch_bounds__(256) void conv2_gate_kernel(
    const uint32_t* __restrict__ h1, const float* __restrict__ x,
    const int* __restrict__ rowptr, const int* __restrict__ csrc,
    const float* __restrict__ cw,
    const ushort* __restrict__ W2f, const float* __restrict__ brel,
    const ushort* __restrict__ Wgf, const float* __restrict__ bsig,
    const float* __restrict__ btanh, const int* __restrict__ batch,
    float* __restrict__ pooled, int n)
{
    __shared__ __align__(16) ushort AH[64 * 136];   // agg2H -> h2H
    __shared__ __align__(16) ushort AL[64 * 136];   // agg2L -> h2L
    __shared__ int bS[64];
    float* gs = (float*)AH;                          // 32KB alias (after barrier)

    int tid = threadIdx.x;
    int lane = tid & 63;
    int wv = tid >> 6;
    int mr = lane & 15;
    int kc = lane >> 4;
    int i0 = blockIdx.x * 64;

    // ---- gather phase: 32 lanes/node, 8 nodes in parallel, 8 iters ----
    {
        int q = tid & 31;
        int g = tid >> 5;
#pragma unroll
        for (int it = 0; it < 8; ++it) {
            int rl = it * 8 + g;
            int node = i0 + rl;
            float4 a = make_float4(0.f, 0.f, 0.f, 0.f);
            if (node < n) {
                int b = rowptr[node], e = rowptr[node + 1];
                int k = b;
                for (; k + 1 < e; k += 2) {
                    int s0 = csrc[k], s1 = csrc[k + 1];
                    float w0 = cw[k], w1 = cw[k + 1];
                    uint4 v0 = *(const uint4*)(h1 + (size_t)s0 * 128 + q * 4);
                    uint4 v1 = *(const uint4*)(h1 + (size_t)s1 * 128 + q * 4);
                    a.x += w0 * unpackval(v0.x); a.y += w0 * unpackval(v0.y);
                    a.z += w0 * unpackval(v0.z); a.w += w0 * unpackval(v0.w);
                    a.x += w1 * unpackval(v1.x); a.y += w1 * unpackval(v1.y);
                    a.z += w1 * unpackval(v1.z); a.w += w1 * unpackval(v1.w);
                }
                if (k < e) {
                    int s0 = csrc[k]; float w0 = cw[k];
                    uint4 v0 = *(const uint4*)(h1 + (size_t)s0 * 128 + q * 4);
                    a.x += w0 * unpackval(v0.x); a.y += w0 * unpackval(v0.y);
                    a.z += w0 * unpackval(v0.z); a.w += w0 * unpackval(v0.w);
                }
            }
            ushort4 hh, ll;
            hh.x = f2bf(a.x); ll.x = f2bf(a.x - bf2f(hh.x));
            hh.y = f2bf(a.y); ll.y = f2bf(a.y - bf2f(hh.y));
            hh.z = f2bf(a.z); ll.z = f2bf(a.z - bf2f(hh.z));
            hh.w = f2bf(a.w); ll.w = f2bf(a.w - bf2f(hh.w));
            *(ushort4*)&AH[rl * 136 + q * 4] = hh;
            *(ushort4*)&AL[rl * 136 + q * 4] = ll;
        }
    }
    if (tid < 64) {
        int r = i0 + tid;
        bS[tid] = (r < n) ? batch[r] : -1;
    }
    __syncthreads();

    int t0 = wv * 2;

    // ---- GEMM1: h2 = leaky([agg2|h1] @ W2 + brel) ----
    f32x4 acc[4][2] = {};
    {
        const ushort* Wp = W2f + kc * 1024 + t0 * 128 + mr * 8;
#pragma unroll
        for (int kk = 0; kk < 4; ++kk) {           // A = LDS agg2 (K 0..127)
            short8 bH0 = *(const short8*)(Wp + kk * 8192);
            short8 bH1 = *(const short8*)(Wp + kk * 8192 + 128);
            short8 bL0 = *(const short8*)(Wp + kk * 8192 + 4096);
            short8 bL1 = *(const short8*)(Wp + kk * 8192 + 4096 + 128);
#pragma unroll
            for (int sub = 0; sub < 4; ++sub) {
                short8 aH = *(const short8*)&AH[(sub * 16 + mr) * 136 + kk * 32 + kc * 8];
                short8 aL = *(const short8*)&AL[(sub * 16 + mr) * 136 + kk * 32 + kc * 8];
                MFMA(acc[sub][0], aH, bH0); MFMA(acc[sub][0], aH, bL0); MFMA(acc[sub][0], aL, bH0);
                MFMA(acc[sub][1], aH, bH1); MFMA(acc[sub][1], aH, bL1); MFMA(acc[sub][1], aL, bH1);
            }
        }
#pragma unroll
        for (int kk = 4; kk < 8; ++kk) {           // A = h1 global (K 128..255)
            short8 bH0 = *(const short8*)(Wp + kk * 8192);
            short8 bH1 = *(const short8*)(Wp + kk * 8192 + 128);
            short8 bL0 = *(const short8*)(Wp + kk * 8192 + 4096);
            short8 bL1 = *(const short8*)(Wp + kk * 8192 + 4096 + 128);
#pragma unroll
            for (int sub = 0; sub < 4; ++sub) {
                int row = i0 + sub * 16 + mr; if (row > n - 1) row = n - 1;
                short8 aH, aL;
                unpack8(h1 + (size_t)row * 128 + (kk - 4) * 32 + kc * 8, aH, aL);
                MFMA(acc[sub][0], aH, bH0); MFMA(acc[sub][0], aH, bL0); MFMA(acc[sub][0], aL, bH0);
                MFMA(acc[sub][1], aH, bH1); MFMA(acc[sub][1], aH, bL1); MFMA(acc[sub][1], aL, bH1);
            }
        }
    }
    __syncthreads();   // agg2 LDS reads complete -> safe to overwrite with h2

#pragma unroll
    for (int tt = 0; tt < 2; ++tt) {
        int c = (t0 + tt) * 16 + mr;
        float bv = brel[c];
#pragma unroll
        for (int sub = 0; sub < 4; ++sub)
#pragma unroll
            for (int j = 0; j < 4; ++j) {
                int rl = sub * 16 + kc * 4 + j;
                float v = LEAKY(acc[sub][tt][j] + bv);
                ushort hi = f2bf(v);
                AH[rl * 136 + c] = hi;
                AL[rl * 136 + c] = f2bf(v - bf2f(hi));
            }
    }
    __syncthreads();

    // ---- GEMM2: gate over [h2|x] ----
    f32x4 as[4][2] = {}, at_[4][2] = {};
    {
        const ushort* Wp = Wgf + kc * 1024 + t0 * 128 + mr * 8;
#pragma unroll
        for (int kk = 0; kk < 4; ++kk) {           // A = LDS h2 (K 0..127)
            short8 sH0 = *(const short8*)(Wp + kk * 16384);
            short8 sH1 = *(const short8*)(Wp + kk * 16384 + 128);
            short8 sL0 = *(const short8*)(Wp + kk * 16384 + 4096);
            short8 sL1 = *(const short8*)(Wp + kk * 16384 + 4096 + 128);
            short8 tH0 = *(const short8*)(Wp + kk * 16384 + 8192);
            short8 tH1 = *(const short8*)(Wp + kk * 16384 + 8192 + 128);
            short8 tL0 = *(const short8*)(Wp + kk * 16384 + 12288);
            short8 tL1 = *(const short8*)(Wp + kk * 16384 + 12288 + 128);
#pragma unroll
            for (int sub = 0; sub < 4; ++sub) {
                short8 aH = *(const short8*)&AH[(sub * 16 + mr) * 136 + kk * 32 + kc * 8];
                short8 aL = *(const short8*)&AL[(sub * 16 + mr) * 136 + kk * 32 + kc * 8];
                MFMA(as[sub][0], aH, sH0); MFMA(as[sub][0], aH, sL0); MFMA(as[sub][0], aL, sH0);
                MFMA(as[sub][1], aH, sH1); MFMA(as[sub][1], aH, sL1); MFMA(as[sub][1], aL, sH1);
                MFMA(at_[sub][0], aH, tH0); MFMA(at_[sub][0], aH, tL0); MFMA(at_[sub][0], aL, tH0);
                MFMA(at_[sub][1], aH, tH1); MFMA(at_[sub][1], aH, tL1); MFMA(at_[sub][1], aL, tH1);
            }
        }
#pragma unroll
        for (int kk = 4; kk < 6; ++kk) {           // A = x (K 128..191)
            short8 sH0 = *(const short8*)(Wp + kk * 16384);
            short8 sH1 = *(const short8*)(Wp + kk * 16384 + 128);
            short8 sL0 = *(const short8*)(Wp + kk * 16384 + 4096);
            short8 sL1 = *(const short8*)(Wp + kk * 16384 + 4096 + 128);
            short8 tH0 = *(const short8*)(Wp + kk * 16384 + 8192);
            short8 tH1 = *(const short8*)(Wp + kk * 16384 + 8192 + 128);
            short8 tL0 = *(const short8*)(Wp + kk * 16384 + 12288);
            short8 tL1 = *(const short8*)(Wp + kk * 16384 + 12288 + 128);
#pragma unroll
            for (int sub = 0; sub < 4; ++sub) {
                int row = i0 + sub * 16 + mr; if (row > n - 1) row = n - 1;
                short8 aH, aL;
                split8(x + (size_t)row * 64 + (kk - 4) * 32 + kc * 8, aH, aL);
                MFMA(as[sub][0], aH, sH0); MFMA(as[sub][0], aH, sL0); MFMA(as[sub][0], aL, sH0);
                MFMA(as[sub][1], aH, sH1); MFMA(as[sub][1], aH, sL1); MFMA(as[sub][1], aL, sH1);
                MFMA(at_[sub][0], aH, tH0); MFMA(at_[sub][0], aH, tL0); MFMA(at_[sub][0], aL, tH0);
                MFMA(at_[sub][1], aH, tH1); MFMA(at_[sub][1], aH, tL1); MFMA(at_[sub][1], aL, tH1);
            }
        }
    }
    __syncthreads();   // h2 LDS reads complete -> safe to alias gs

    // ---- gate epilogue ----
#pragma unroll
    for (int tt = 0; tt < 2; ++tt) {
        int c = (t0 + tt) * 16 + mr;
        float bsv = bsig[c], btv = btanh[c];
#pragma unroll
        for (int sub = 0; sub < 4; ++sub)
#pragma unroll
            for (int j = 0; j < 4; ++j) {
                int rl = sub * 16 + kc * 4 + j;
                float s = as[sub][tt][j] + bsv;
                s = fminf(fmaxf(s, -30.f), 30.f);
                float ta = at_[sub][tt][j] + btv;
                ta = fminf(fmaxf(ta, -15.f), 15.f);
                float e2 = __expf(2.f * ta);
                float th = (e2 - 1.f) / (e2 + 1.f);
                gs[rl * 128 + c] = th / (1.f + __expf(s));
            }
    }
    __syncthreads();

    // ---- run-compressed pooling ----
    int j = tid & 127;
    int m0 = (tid >> 7) * 32;
    float acc2 = 0.f;
    int cur = -1;
    for (int m = m0; m < m0 + 32; ++m) {
        int b = bS[m];
        if (b < 0) break;
        if (b != cur) {
            if (cur >= 0) atomicAdd(&pooled[(size_t)cur * 128 + j], acc2);
            cur = b;
            acc2 = 0.f;
        }
        acc2 += gs[m * 128 + j];
    }
    if (cur >= 0) atomicAdd(&pooled[(size_t)cur * 128 + j], acc2);
}

// ---------------------------------------------------------------------------
// Final per-graph MLP
// ---------------------------------------------------------------------------
__global__ __launch_bounds__(256) void mlp_kernel(
    const float* __restrict__ pooled,
    const float* __restrict__ Wf1, const float* __restrict__ bf1,
    const float* __restrict__ Wf2, const float* __restrict__ bf2,
    const float* __restrict__ Wout, const float* __restrict__ bout,
    float* __restrict__ out)
{
    __shared__ float p[128];
    __shared__ float f1[128];
    __shared__ float f2[258];
    __shared__ float red[4];

    int g = blockIdx.x;
    int tid = threadIdx.x;

    if (tid < 128) p[tid] = pooled[(size_t)g * 128 + tid];
    __syncthreads();

    if (tid < 128) {
        float a = bf1[tid];
        for (int k = 0; k < 128; ++k) a += p[k] * Wf1[k * 128 + tid];
        f1[tid] = LEAKY(a);
    }
    __syncthreads();

    for (int j = tid; j < 258; j += 256) {
        float a = bf2[j];
        for (int k = 0; k < 128; ++k) a += f1[k] * Wf2[k * 258 + j];
        f2[j] = LEAKY(a);
    }
    __syncthreads();

    float a = 0.f;
    for (int j = tid; j < 258; j += 256) a += f2[j] * Wout[j];
#pragma unroll
    for (int off = 32; off > 0; off >>= 1) a += __shfl_down(a, off, 64);
    if ((tid & 63) == 0) red[tid >> 6] = a;
    __syncthreads();
    if (tid == 0) {
        float v = red[0] + red[1] + red[2] + red[3] + bout[0];
        out[g] = 1.f / (1.f + expf(-v));
    }
}

// ---------------------------------------------------------------------------
extern "C" void kernel_launch(void* const* d_in, const int* in_sizes, int n_in,
                              void* d_out, int out_size, void* d_ws, size_t ws_size,
                              hipStream_t stream)
{
    const float* x     = (const float*)d_in[0];
    const int*   ei    = (const int*)d_in[1];
    const int*   batch = (const int*)d_in[2];
    const float* ea    = (const float*)d_in[3];
    const float* Wrel1 = (const float*)d_in[4];
    const float* brel1 = (const float*)d_in[5];
    const float* Wroot1= (const float*)d_in[6];
    const float* Wrel2 = (const float*)d_in[7];
    const float* brel2 = (const float*)d_in[8];
    const float* Wroot2= (const float*)d_in[9];
    const float* Wsig  = (const float*)d_in[10];
    const float* bsig  = (const float*)d_in[11];
    const float* Wtanh = (const float*)d_in[12];
    const float* btanh = (const float*)d_in[13];
    const float* Wf1   = (const float*)d_in[14];
    const float* bf1   = (const float*)d_in[15];
    const float* Wf2   = (const float*)d_in[16];
    const float* bf2   = (const float*)d_in[17];
    const float* Wout  = (const float*)d_in[18];
    const float* bout  = (const float*)d_in[19];

    int N = in_sizes[2];
    int E = in_sizes[3];

    char* base = (char*)d_ws;
    size_t off = 0;
    auto alloc = [&](size_t bytes) {
        char* p = base + off;
        off += (bytes + 255) & ~(size_t)255;
        return p;
    };
    uint32_t* h1    = (uint32_t*)alloc((size_t)N * 128 * 4);
    int*      rowptr= (int*)alloc((size_t)(N + 1) * 4);
    int*      cursor= (int*)alloc((size_t)N * 4);
    int*      bsum  = (int*)alloc(512 * 4);
    int*      csrc  = (int*)alloc((size_t)E * 4);
    float*    cwgt  = (float*)alloc((size_t)E * 4);
    ushort*   W1f   = (ushort*)alloc(32768 * 2);
    ushort*   W2f   = (ushort*)alloc(65536 * 2);
    ushort*   Wgf   = (ushort*)alloc(98304 * 2);
    float*    pooled= (float*)alloc(256 * 128 * 4);

    int eblk = (E + 255) / 256;
    int nblk1 = (N + 1023) / 1024;
    int cblk = (N + 63) / 64;

    hipMemsetAsync(cursor, 0, (size_t)N * sizeof(int), stream);
    hipMemsetAsync(pooled, 0, (size_t)256 * 128 * sizeof(float), stream);

    prep_weights_kernel<<<768, 256, 0, stream>>>(Wrel1, Wroot1, Wrel2, Wroot2,
                                                 Wsig, Wtanh, W1f, W2f, Wgf);

    // ---- CSR build ----
    hist_kernel<<<eblk, 256, 0, stream>>>(ei, cursor, E);
    scan1_kernel<<<nblk1, 256, 0, stream>>>(cursor, rowptr, bsum, N);
    scan2_kernel<<<1, 512, 0, stream>>>(bsum, nblk1);
    scan3_kernel<<<(N + 255) / 256, 256, 0, stream>>>(rowptr, bsum, N, E);
    hipMemcpyAsync(cursor, rowptr, (size_t)N * sizeof(int),
                   hipMemcpyDeviceToDevice, stream);
    fill_kernel<<<eblk, 256, 0, stream>>>(ei, ea, cursor, csrc, cwgt, E);

    // ---- fused conv1 (gather + GEMM) ----
    conv1_fused_kernel<<<cblk, 256, 0, stream>>>(x, rowptr, csrc, cwgt,
                                                 W1f, brel1, h1, N);

    // ---- fused conv2 + gate + pool (gather + 2 GEMMs) ----
    conv2_gate_kernel<<<cblk, 256, 0, stream>>>(h1, x, rowptr, csrc, cwgt,
                                                W2f, brel2, Wgf, bsig, btanh,
                                                batch, pooled, N);

    // ---- final MLP ----
    mlp_kernel<<<256, 256, 0, stream>>>(pooled, Wf1, bf1, Wf2, bf2, Wout, bout,
                                        (float*)d_out);
}

// Round 5
// 558.097 us; speedup vs baseline: 2.5717x; 1.1585x over previous
//
#include <hip/hip_runtime.h>
#include <cstdint>

#define RELU_COEF 0.05f
#define LEAKY(v) ((v) > 0.f ? (v) : RELU_COEF * (v))

typedef __attribute__((ext_vector_type(8))) short short8;
typedef __attribute__((ext_vector_type(4))) float f32x4;

#define MFMA(acc, a, b) \
    acc = __builtin_amdgcn_mfma_f32_16x16x32_bf16(a, b, acc, 0, 0, 0)

__device__ inline ushort f2bf(float f) {
    union { float f; uint32_t u; } v; v.f = f;
    return (ushort)((v.u + 0x7FFFu + ((v.u >> 16) & 1u)) >> 16);
}
__device__ inline float bf2f(ushort h) {
    union { uint32_t u; float f; } v; v.u = ((uint32_t)h) << 16;
    return v.f;
}
__device__ inline uint32_t packsplit(float v) {
    ushort hi = f2bf(v);
    ushort lo = f2bf(v - bf2f(hi));
    return ((uint32_t)hi << 16) | (uint32_t)lo;
}
__device__ inline float unpackval(uint32_t v) {
    union { uint32_t u; float f; } a, b;
    a.u = v & 0xFFFF0000u;
    b.u = v << 16;
    return a.f + b.f;
}
__device__ inline void split8(const float* p, short8& h8, short8& l8) {
    float4 a = *(const float4*)p;
    float4 b = *(const float4*)(p + 4);
    float v[8] = {a.x, a.y, a.z, a.w, b.x, b.y, b.z, b.w};
    short8 hh, ll;
#pragma unroll
    for (int i = 0; i < 8; ++i) {
        ushort hi = f2bf(v[i]);
        hh[i] = (short)hi;
        ll[i] = (short)f2bf(v[i] - bf2f(hi));
    }
    h8 = hh; l8 = ll;
}
__device__ inline void unpack8(const uint32_t* p, short8& h8, short8& l8) {
    uint4 a = *(const uint4*)p;
    uint4 b = *(const uint4*)(p + 4);
    union { uint32_t u[4]; short8 s; } H, L;
    uint32_t v0, v1;
    v0 = a.x; v1 = a.y; H.u[0] = (v0 >> 16) | (v1 & 0xFFFF0000u); L.u[0] = (v0 & 0xFFFFu) | (v1 << 16);
    v0 = a.z; v1 = a.w; H.u[1] = (v0 >> 16) | (v1 & 0xFFFF0000u); L.u[1] = (v0 & 0xFFFFu) | (v1 << 16);
    v0 = b.x; v1 = b.y; H.u[2] = (v0 >> 16) | (v1 & 0xFFFF0000u); L.u[2] = (v0 & 0xFFFFu) | (v1 << 16);
    v0 = b.z; v1 = b.w; H.u[3] = (v0 >> 16) | (v1 & 0xFFFF0000u); L.u[3] = (v0 & 0xFFFFu) | (v1 << 16);
    h8 = H.s; l8 = L.s;
}

// ---------------------------------------------------------------------------
// CSR build
// ---------------------------------------------------------------------------
__global__ __launch_bounds__(256) void hist_kernel(
    const int* __restrict__ ei, int* __restrict__ deg, int E)
{
    int e = blockIdx.x * 256 + threadIdx.x;
    if (e >= E) return;
    atomicAdd(&deg[ei[(size_t)E + e]], 1);
}

__global__ __launch_bounds__(256) void scan1_kernel(
    const int* __restrict__ in, int* __restrict__ out, int* __restrict__ bsum, int N)
{
    __shared__ int ts[256];
    int tid = threadIdx.x;
    int base = blockIdx.x * 1024 + tid * 4;
    int v[4];
    int s = 0;
#pragma unroll
    for (int j = 0; j < 4; ++j) {
        int idx = base + j;
        v[j] = (idx < N) ? in[idx] : 0;
        s += v[j];
    }
    ts[tid] = s;
    __syncthreads();
    for (int off = 1; off < 256; off <<= 1) {
        int t = (tid >= off) ? ts[tid - off] : 0;
        __syncthreads();
        ts[tid] += t;
        __syncthreads();
    }
    int excl = ts[tid] - s;
    if (tid == 255) bsum[blockIdx.x] = ts[255];
    int run = excl;
#pragma unroll
    for (int j = 0; j < 4; ++j) {
        int idx = base + j;
        if (idx < N) out[idx] = run;
        run += v[j];
    }
}

__global__ __launch_bounds__(512) void scan2_kernel(int* bsum, int nb)
{
    __shared__ int ts[512];
    int tid = threadIdx.x;
    int v = (tid < nb) ? bsum[tid] : 0;
    ts[tid] = v;
    __syncthreads();
    for (int off = 1; off < 512; off <<= 1) {
        int t = (tid >= off) ? ts[tid - off] : 0;
        __syncthreads();
        ts[tid] += t;
        __syncthreads();
    }
    if (tid < nb) bsum[tid] = ts[tid] - v;
}

__global__ __launch_bounds__(256) void scan3_kernel(
    int* __restrict__ rowptr, const int* __restrict__ bsum, int N, int E)
{
    int idx = blockIdx.x * 256 + threadIdx.x;
    if (idx < N) rowptr[idx] += bsum[idx >> 10];
    if (idx == 0) rowptr[N] = E;
}

__global__ __launch_bounds__(256) void fill_kernel(
    const int* __restrict__ ei, const float* __restrict__ ea,
    int* __restrict__ cursor, int* __restrict__ csrc, float* __restrict__ cw, int E)
{
    int e = blockIdx.x * 256 + threadIdx.x;
    if (e >= E) return;
    int t = ei[(size_t)E + e];
    int pos = atomicAdd(&cursor[t], 1);
    csrc[pos] = ei[e];
    cw[pos] = ea[e];
}

// ---------------------------------------------------------------------------
// Weight prep -> fragment-major split-bf16 layouts (coalesced B loads):
// W1f[kk:4][hl:2][kc:4][n:128][e:8]   (K=128: agg1|x)
// W2f[kk:8][hl:2][kc:4][n:128][e:8]   (K=256: agg2|h1)
// Wgf[kk:6][p:4 (sH,sL,tH,tL)][kc:4][n:128][e:8]  (K=192: h2|x)
// ---------------------------------------------------------------------------
__global__ __launch_bounds__(256) void prep_weights_kernel(
    const float* __restrict__ Wrel1, const float* __restrict__ Wroot1,
    const float* __restrict__ Wrel2, const float* __restrict__ Wroot2,
    const float* __restrict__ Wsig, const float* __restrict__ Wtanh,
    ushort* __restrict__ W1f, ushort* __restrict__ W2f, ushort* __restrict__ Wgf)
{
    int gid = blockIdx.x * 256 + threadIdx.x;
    if (gid < 32768) {
        int e = gid & 7, nn = (gid >> 3) & 127, kc = (gid >> 10) & 3;
        int hl = (gid >> 12) & 1, kk = gid >> 13;
        int k = kk * 32 + kc * 8 + e;
        float v = (k < 64) ? Wrel1[(size_t)k * 128 + nn]
                           : Wroot1[(size_t)(k - 64) * 128 + nn];
        ushort hi = f2bf(v);
        W1f[gid] = hl ? f2bf(v - bf2f(hi)) : hi;
        return;
    }
    int g2 = gid - 32768;
    if (g2 < 65536) {
        int e = g2 & 7, nn = (g2 >> 3) & 127, kc = (g2 >> 10) & 3;
        int hl = (g2 >> 12) & 1, kk = g2 >> 13;
        int k = kk * 32 + kc * 8 + e;
        float v = (k < 128) ? Wrel2[(size_t)k * 128 + nn]
                            : Wroot2[(size_t)(k - 128) * 128 + nn];
        ushort hi = f2bf(v);
        W2f[g2] = hl ? f2bf(v - bf2f(hi)) : hi;
        return;
    }
    int g3 = g2 - 65536;
    if (g3 < 98304) {
        int e = g3 & 7, nn = (g3 >> 3) & 127, kc = (g3 >> 10) & 3;
        int p = (g3 >> 12) & 3, kk = g3 >> 14;
        int k = kk * 32 + kc * 8 + e;
        float v = (p < 2) ? Wsig[(size_t)k * 128 + nn]
                          : Wtanh[(size_t)k * 128 + nn];
        ushort hi = f2bf(v);
        Wgf[g3] = (p & 1) ? f2bf(v - bf2f(hi)) : hi;
    }
}

// ---------------------------------------------------------------------------
// Fused conv1: gather(x) -> LDS planes; h1 = packsplit(leaky([agg1|x]@W1 + b))
// Gather: 16 lanes/node; edge (idx,w) prefetched into lane regs, shfl-broadcast,
// 4-deep unrolled independent row loads.
// ---------------------------------------------------------------------------
__global__ __launch_bounds__(256) void conv1_fused_kernel(
    const float* __restrict__ x, const int* __restrict__ rowptr,
    const int* __restrict__ csrc, const float* __restrict__ cw,
    const ushort* __restrict__ W1f, const float* __restrict__ brel,
    uint32_t* __restrict__ h1, int n)
{
    __shared__ __align__(16) ushort AH[64 * 72];
    __shared__ __align__(16) ushort AL[64 * 72];

    int tid = threadIdx.x;
    int lane = tid & 63;
    int wv = tid >> 6;
    int mr = lane & 15;
    int kc = lane >> 4;          // 0..3
    int i0 = blockIdx.x * 64;

    // ---- gather phase ----
    {
        int q = tid & 15;
        int g = tid >> 4;
#pragma unroll
        for (int it = 0; it < 4; ++it) {
            int rl = it * 16 + g;
            int node = i0 + rl;
            float ax = 0.f, ay = 0.f, az = 0.f, aw = 0.f;
            if (node < n) {
                int b = rowptr[node], e = rowptr[node + 1];
                for (int cb = b; cb < e; cb += 16) {
                    int cnt = e - cb; if (cnt > 16) cnt = 16;
                    int sIdx = 0; float sW = 0.f;
                    if (q < cnt) { sIdx = csrc[cb + q]; sW = cw[cb + q]; }
                    int j = 0;
                    for (; j + 4 <= cnt; j += 4) {
                        int s0 = __shfl(sIdx, j + 0, 16); float w0 = __shfl(sW, j + 0, 16);
                        int s1 = __shfl(sIdx, j + 1, 16); float w1 = __shfl(sW, j + 1, 16);
                        int s2 = __shfl(sIdx, j + 2, 16); float w2 = __shfl(sW, j + 2, 16);
                        int s3 = __shfl(sIdx, j + 3, 16); float w3 = __shfl(sW, j + 3, 16);
                        float4 f0 = *(const float4*)(x + (size_t)s0 * 64 + q * 4);
                        float4 f1 = *(const float4*)(x + (size_t)s1 * 64 + q * 4);
                        float4 f2 = *(const float4*)(x + (size_t)s2 * 64 + q * 4);
                        float4 f3 = *(const float4*)(x + (size_t)s3 * 64 + q * 4);
                        ax += w0 * f0.x + w1 * f1.x + w2 * f2.x + w3 * f3.x;
                        ay += w0 * f0.y + w1 * f1.y + w2 * f2.y + w3 * f3.y;
                        az += w0 * f0.z + w1 * f1.z + w2 * f2.z + w3 * f3.z;
                        aw += w0 * f0.w + w1 * f1.w + w2 * f2.w + w3 * f3.w;
                    }
                    for (; j < cnt; ++j) {
                        int s0 = __shfl(sIdx, j, 16); float w0 = __shfl(sW, j, 16);
                        float4 f0 = *(const float4*)(x + (size_t)s0 * 64 + q * 4);
                        ax += w0 * f0.x; ay += w0 * f0.y; az += w0 * f0.z; aw += w0 * f0.w;
                    }
                }
            }
            ushort4 hh, ll;
            hh.x = f2bf(ax); ll.x = f2bf(ax - bf2f(hh.x));
            hh.y = f2bf(ay); ll.y = f2bf(ay - bf2f(hh.y));
            hh.z = f2bf(az); ll.z = f2bf(az - bf2f(hh.z));
            hh.w = f2bf(aw); ll.w = f2bf(aw - bf2f(hh.w));
            *(ushort4*)&AH[rl * 72 + q * 4] = hh;
            *(ushort4*)&AL[rl * 72 + q * 4] = ll;
        }
    }
    __syncthreads();

    // ---- GEMM ----
    int t0 = wv * 2;
    const ushort* Wp = W1f + kc * 1024 + t0 * 128 + mr * 8;
    f32x4 acc[4][2] = {};

#pragma unroll
    for (int kk = 0; kk < 2; ++kk) {      // A from LDS agg1 (K 0..63)
        short8 bH0 = *(const short8*)(Wp + kk * 8192);
        short8 bH1 = *(const short8*)(Wp + kk * 8192 + 128);
        short8 bL0 = *(const short8*)(Wp + kk * 8192 + 4096);
        short8 bL1 = *(const short8*)(Wp + kk * 8192 + 4096 + 128);
#pragma unroll
        for (int sub = 0; sub < 4; ++sub) {
            short8 aH = *(const short8*)&AH[(sub * 16 + mr) * 72 + kk * 32 + kc * 8];
            short8 aL = *(const short8*)&AL[(sub * 16 + mr) * 72 + kk * 32 + kc * 8];
            MFMA(acc[sub][0], aH, bH0); MFMA(acc[sub][0], aH, bL0); MFMA(acc[sub][0], aL, bH0);
            MFMA(acc[sub][1], aH, bH1); MFMA(acc[sub][1], aH, bL1); MFMA(acc[sub][1], aL, bH1);
        }
    }
#pragma unroll
    for (int kk = 2; kk < 4; ++kk) {      // A from x (K 64..127)
        short8 bH0 = *(const short8*)(Wp + kk * 8192);
        short8 bH1 = *(const short8*)(Wp + kk * 8192 + 128);
        short8 bL0 = *(const short8*)(Wp + kk * 8192 + 4096);
        short8 bL1 = *(const short8*)(Wp + kk * 8192 + 4096 + 128);
#pragma unroll
        for (int sub = 0; sub < 4; ++sub) {
            int row = i0 + sub * 16 + mr; if (row > n - 1) row = n - 1;
            short8 aH, aL;
            split8(x + (size_t)row * 64 + (kk - 2) * 32 + kc * 8, aH, aL);
            MFMA(acc[sub][0], aH, bH0); MFMA(acc[sub][0], aH, bL0); MFMA(acc[sub][0], aL, bH0);
            MFMA(acc[sub][1], aH, bH1); MFMA(acc[sub][1], aH, bL1); MFMA(acc[sub][1], aL, bH1);
        }
    }

#pragma unroll
    for (int tt = 0; tt < 2; ++tt) {
        int c = (t0 + tt) * 16 + mr;
        float bv = brel[c];
#pragma unroll
        for (int sub = 0; sub < 4; ++sub)
#pragma unroll
            for (int j = 0; j < 4; ++j) {
                int r = i0 + sub * 16 + kc * 4 + j;
                if (r < n)
                    h1[(size_t)r * 128 + c] = packsplit(LEAKY(acc[sub][tt][j] + bv));
            }
    }
}

// ---------------------------------------------------------------------------
// Fused conv2 + gate + pool (shfl-broadcast gather, then 2 GEMMs + pooling)
// ---------------------------------------------------------------------------
__global__ __launch_bounds__(256) void conv2_gate_kernel(
    const uint32_t* __restrict__ h1, const float* __restrict__ x,
    const int* __restrict__ rowptr, const int* __restrict__ csrc,
    const float* __restrict__ cw,
    const ushort* __restrict__ W2f, const float* __restrict__ brel,
    const ushort* __restrict__ Wgf, const float* __restrict__ bsig,
    const float* __restrict__ btanh, const int* __restrict__ batch,
    float* __restrict__ pooled, int n)
{
    __shared__ __align__(16) ushort AH[64 * 136];   // agg2H -> h2H
    __shared__ __align__(16) ushort AL[64 * 136];   // agg2L -> h2L
    __shared__ int bS[64];
    float* gs = (float*)AH;                          // 32KB alias (after barrier)

    int tid = threadIdx.x;
    int lane = tid & 63;
    int wv = tid >> 6;
    int mr = lane & 15;
    int kc = lane >> 4;
    int i0 = blockIdx.x * 64;

    // ---- gather phase: 32 lanes/node, prefetched indices, 4-deep loads ----
    {
        int q = tid & 31;
        int g = tid >> 5;
#pragma unroll
        for (int it = 0; it < 8; ++it) {
            int rl = it * 8 + g;
            int node = i0 + rl;
            float ax = 0.f, ay = 0.f, az = 0.f, aw = 0.f;
            if (node < n) {
                int b = rowptr[node], e = rowptr[node + 1];
                for (int cb = b; cb < e; cb += 32) {
                    int cnt = e - cb; if (cnt > 32) cnt = 32;
                    int sIdx = 0; float sW = 0.f;
                    if (q < cnt) { sIdx = csrc[cb + q]; sW = cw[cb + q]; }
                    int j = 0;
                    for (; j + 4 <= cnt; j += 4) {
                        int s0 = __shfl(sIdx, j + 0, 32); float w0 = __shfl(sW, j + 0, 32);
                        int s1 = __shfl(sIdx, j + 1, 32); float w1 = __shfl(sW, j + 1, 32);
                        int s2 = __shfl(sIdx, j + 2, 32); float w2 = __shfl(sW, j + 2, 32);
                        int s3 = __shfl(sIdx, j + 3, 32); float w3 = __shfl(sW, j + 3, 32);
                        uint4 v0 = *(const uint4*)(h1 + (size_t)s0 * 128 + q * 4);
                        uint4 v1 = *(const uint4*)(h1 + (size_t)s1 * 128 + q * 4);
                        uint4 v2 = *(const uint4*)(h1 + (size_t)s2 * 128 + q * 4);
                        uint4 v3 = *(const uint4*)(h1 + (size_t)s3 * 128 + q * 4);
                        ax += w0 * unpackval(v0.x) + w1 * unpackval(v1.x)
                            + w2 * unpackval(v2.x) + w3 * unpackval(v3.x);
                        ay += w0 * unpackval(v0.y) + w1 * unpackval(v1.y)
                            + w2 * unpackval(v2.y) + w3 * unpackval(v3.y);
                        az += w0 * unpackval(v0.z) + w1 * unpackval(v1.z)
                            + w2 * unpackval(v2.z) + w3 * unpackval(v3.z);
                        aw += w0 * unpackval(v0.w) + w1 * unpackval(v1.w)
                            + w2 * unpackval(v2.w) + w3 * unpackval(v3.w);
                    }
                    for (; j < cnt; ++j) {
                        int s0 = __shfl(sIdx, j, 32); float w0 = __shfl(sW, j, 32);
                        uint4 v0 = *(const uint4*)(h1 + (size_t)s0 * 128 + q * 4);
                        ax += w0 * unpackval(v0.x); ay += w0 * unpackval(v0.y);
                        az += w0 * unpackval(v0.z); aw += w0 * unpackval(v0.w);
                    }
                }
            }
            ushort4 hh, ll;
            hh.x = f2bf(ax); ll.x = f2bf(ax - bf2f(hh.x));
            hh.y = f2bf(ay); ll.y = f2bf(ay - bf2f(hh.y));
            hh.z = f2bf(az); ll.z = f2bf(az - bf2f(hh.z));
            hh.w = f2bf(aw); ll.w = f2bf(aw - bf2f(hh.w));
            *(ushort4*)&AH[rl * 136 + q * 4] = hh;
            *(ushort4*)&AL[rl * 136 + q * 4] = ll;
        }
    }
    if (tid < 64) {
        int r = i0 + tid;
        bS[tid] = (r < n) ? batch[r] : -1;
    }
    __syncthreads();

    int t0 = wv * 2;

    // ---- GEMM1: h2 = leaky([agg2|h1] @ W2 + brel) ----
    f32x4 acc[4][2] = {};
    {
        const ushort* Wp = W2f + kc * 1024 + t0 * 128 + mr * 8;
#pragma unroll
        for (int kk = 0; kk < 4; ++kk) {           // A = LDS agg2 (K 0..127)
            short8 bH0 = *(const short8*)(Wp + kk * 8192);
            short8 bH1 = *(const short8*)(Wp + kk * 8192 + 128);
            short8 bL0 = *(const short8*)(Wp + kk * 8192 + 4096);
            short8 bL1 = *(const short8*)(Wp + kk * 8192 + 4096 + 128);
#pragma unroll
            for (int sub = 0; sub < 4; ++sub) {
                short8 aH = *(const short8*)&AH[(sub * 16 + mr) * 136 + kk * 32 + kc * 8];
                short8 aL = *(const short8*)&AL[(sub * 16 + mr) * 136 + kk * 32 + kc * 8];
                MFMA(acc[sub][0], aH, bH0); MFMA(acc[sub][0], aH, bL0); MFMA(acc[sub][0], aL, bH0);
                MFMA(acc[sub][1], aH, bH1); MFMA(acc[sub][1], aH, bL1); MFMA(acc[sub][1], aL, bH1);
            }
        }
#pragma unroll
        for (int kk = 4; kk < 8; ++kk) {           // A = h1 global (K 128..255)
            short8 bH0 = *(const short8*)(Wp + kk * 8192);
            short8 bH1 = *(const short8*)(Wp + kk * 8192 + 128);
            short8 bL0 = *(const short8*)(Wp + kk * 8192 + 4096);
            short8 bL1 = *(const short8*)(Wp + kk * 8192 + 4096 + 128);
#pragma unroll
            for (int sub = 0; sub < 4; ++sub) {
                int row = i0 + sub * 16 + mr; if (row > n - 1) row = n - 1;
                short8 aH, aL;
                unpack8(h1 + (size_t)row * 128 + (kk - 4) * 32 + kc * 8, aH, aL);
                MFMA(acc[sub][0], aH, bH0); MFMA(acc[sub][0], aH, bL0); MFMA(acc[sub][0], aL, bH0);
                MFMA(acc[sub][1], aH, bH1); MFMA(acc[sub][1], aH, bL1); MFMA(acc[sub][1], aL, bH1);
            }
        }
    }
    __syncthreads();   // agg2 LDS reads complete -> safe to overwrite with h2

#pragma unroll
    for (int tt = 0; tt < 2; ++tt) {
        int c = (t0 + tt) * 16 + mr;
        float bv = brel[c];
#pragma unroll
        for (int sub = 0; sub < 4; ++sub)
#pragma unroll
            for (int j = 0; j < 4; ++j) {
                int rl = sub * 16 + kc * 4 + j;
                float v = LEAKY(acc[sub][tt][j] + bv);
                ushort hi = f2bf(v);
                AH[rl * 136 + c] = hi;
                AL[rl * 136 + c] = f2bf(v - bf2f(hi));
            }
    }
    __syncthreads();

    // ---- GEMM2: gate over [h2|x] ----
    f32x4 as[4][2] = {}, at_[4][2] = {};
    {
        const ushort* Wp = Wgf + kc * 1024 + t0 * 128 + mr * 8;
#pragma unroll
        for (int kk = 0; kk < 4; ++kk) {           // A = LDS h2 (K 0..127)
            short8 sH0 = *(const short8*)(Wp + kk * 16384);
            short8 sH1 = *(const short8*)(Wp + kk * 16384 + 128);
            short8 sL0 = *(const short8*)(Wp + kk * 16384 + 4096);
            short8 sL1 = *(const short8*)(Wp + kk * 16384 + 4096 + 128);
            short8 tH0 = *(const short8*)(Wp + kk * 16384 + 8192);
            short8 tH1 = *(const short8*)(Wp + kk * 16384 + 8192 + 128);
            short8 tL0 = *(const short8*)(Wp + kk * 16384 + 12288);
            short8 tL1 = *(const short8*)(Wp + kk * 16384 + 12288 + 128);
#pragma unroll
            for (int sub = 0; sub < 4; ++sub) {
                short8 aH = *(const short8*)&AH[(sub * 16 + mr) * 136 + kk * 32 + kc * 8];
                short8 aL = *(const short8*)&AL[(sub * 16 + mr) * 136 + kk * 32 + kc * 8];
                MFMA(as[sub][0], aH, sH0); MFMA(as[sub][0], aH, sL0); MFMA(as[sub][0], aL, sH0);
                MFMA(as[sub][1], aH, sH1); MFMA(as[sub][1], aH, sL1); MFMA(as[sub][1], aL, sH1);
                MFMA(at_[sub][0], aH, tH0); MFMA(at_[sub][0], aH, tL0); MFMA(at_[sub][0], aL, tH0);
                MFMA(at_[sub][1], aH, tH1); MFMA(at_[sub][1], aH, tL1); MFMA(at_[sub][1], aL, tH1);
            }
        }
#pragma unroll
        for (int kk = 4; kk < 6; ++kk) {           // A = x (K 128..191)
            short8 sH0 = *(const short8*)(Wp + kk * 16384);
            short8 sH1 = *(const short8*)(Wp + kk * 16384 + 128);
            short8 sL0 = *(const short8*)(Wp + kk * 16384 + 4096);
            short8 sL1 = *(const short8*)(Wp + kk * 16384 + 4096 + 128);
            short8 tH0 = *(const short8*)(Wp + kk * 16384 + 8192);
            short8 tH1 = *(const short8*)(Wp + kk * 16384 + 8192 + 128);
            short8 tL0 = *(const short8*)(Wp + kk * 16384 + 12288);
            short8 tL1 = *(const short8*)(Wp + kk * 16384 + 12288 + 128);
#pragma unroll
            for (int sub = 0; sub < 4; ++sub) {
                int row = i0 + sub * 16 + mr; if (row > n - 1) row = n - 1;
                short8 aH, aL;
                split8(x + (size_t)row * 64 + (kk - 4) * 32 + kc * 8, aH, aL);
                MFMA(as[sub][0], aH, sH0); MFMA(as[sub][0], aH, sL0); MFMA(as[sub][0], aL, sH0);
                MFMA(as[sub][1], aH, sH1); MFMA(as[sub][1], aH, sL1); MFMA(as[sub][1], aL, sH1);
                MFMA(at_[sub][0], aH, tH0); MFMA(at_[sub][0], aH, tL0); MFMA(at_[sub][0], aL, tH0);
                MFMA(at_[sub][1], aH, tH1); MFMA(at_[sub][1], aH, tL1); MFMA(at_[sub][1], aL, tH1);
            }
        }
    }
    __syncthreads();   // h2 LDS reads complete -> safe to alias gs

    // ---- gate epilogue ----
#pragma unroll
    for (int tt = 0; tt < 2; ++tt) {
        int c = (t0 + tt) * 16 + mr;
        float bsv = bsig[c], btv = btanh[c];
#pragma unroll
        for (int sub = 0; sub < 4; ++sub)
#pragma unroll
            for (int j = 0; j < 4; ++j) {
                int rl = sub * 16 + kc * 4 + j;
                float s = as[sub][tt][j] + bsv;
                s = fminf(fmaxf(s, -30.f), 30.f);
                float ta = at_[sub][tt][j] + btv;
                ta = fminf(fmaxf(ta, -15.f), 15.f);
                float e2 = __expf(2.f * ta);
                float th = (e2 - 1.f) / (e2 + 1.f);
                gs[rl * 128 + c] = th / (1.f + __expf(s));
            }
    }
    __syncthreads();

    // ---- run-compressed pooling ----
    int j = tid & 127;
    int m0 = (tid >> 7) * 32;
    float acc2 = 0.f;
    int cur = -1;
    for (int m = m0; m < m0 + 32; ++m) {
        int b = bS[m];
        if (b < 0) break;
        if (b != cur) {
            if (cur >= 0) atomicAdd(&pooled[(size_t)cur * 128 + j], acc2);
            cur = b;
            acc2 = 0.f;
        }
        acc2 += gs[m * 128 + j];
    }
    if (cur >= 0) atomicAdd(&pooled[(size_t)cur * 128 + j], acc2);
}

// ---------------------------------------------------------------------------
// Final per-graph MLP
// ---------------------------------------------------------------------------
__global__ __launch_bounds__(256) void mlp_kernel(
    const float* __restrict__ pooled,
    const float* __restrict__ Wf1, const float* __restrict__ bf1,
    const float* __restrict__ Wf2, const float* __restrict__ bf2,
    const float* __restrict__ Wout, const float* __restrict__ bout,
    float* __restrict__ out)
{
    __shared__ float p[128];
    __shared__ float f1[128];
    __shared__ float f2[258];
    __shared__ float red[4];

    int g = blockIdx.x;
    int tid = threadIdx.x;

    if (tid < 128) p[tid] = pooled[(size_t)g * 128 + tid];
    __syncthreads();

    if (tid < 128) {
        float a = bf1[tid];
        for (int k = 0; k < 128; ++k) a += p[k] * Wf1[k * 128 + tid];
        f1[tid] = LEAKY(a);
    }
    __syncthreads();

    for (int j = tid; j < 258; j += 256) {
        float a = bf2[j];
        for (int k = 0; k < 128; ++k) a += f1[k] * Wf2[k * 258 + j];
        f2[j] = LEAKY(a);
    }
    __syncthreads();

    float a = 0.f;
    for (int j = tid; j < 258; j += 256) a += f2[j] * Wout[j];
#pragma unroll
    for (int off = 32; off > 0; off >>= 1) a += __shfl_down(a, off, 64);
    if ((tid & 63) == 0) red[tid >> 6] = a;
    __syncthreads();
    if (tid == 0) {
        float v = red[0] + red[1] + red[2] + red[3] + bout[0];
        out[g] = 1.f / (1.f + expf(-v));
    }
}

// ---------------------------------------------------------------------------
extern "C" void kernel_launch(void* const* d_in, const int* in_sizes, int n_in,
                              void* d_out, int out_size, void* d_ws, size_t ws_size,
                              hipStream_t stream)
{
    const float* x     = (const float*)d_in[0];
    const int*   ei    = (const int*)d_in[1];
    const int*   batch = (const int*)d_in[2];
    const float* ea    = (const float*)d_in[3];
    const float* Wrel1 = (const float*)d_in[4];
    const float* brel1 = (const float*)d_in[5];
    const float* Wroot1= (const float*)d_in[6];
    const float* Wrel2 = (const float*)d_in[7];
    const float* brel2 = (const float*)d_in[8];
    const float* Wroot2= (const float*)d_in[9];
    const float* Wsig  = (const float*)d_in[10];
    const float* bsig  = (const float*)d_in[11];
    const float* Wtanh = (const float*)d_in[12];
    const float* btanh = (const float*)d_in[13];
    const float* Wf1   = (const float*)d_in[14];
    const float* bf1   = (const float*)d_in[15];
    const float* Wf2   = (const float*)d_in[16];
    const float* bf2   = (const float*)d_in[17];
    const float* Wout  = (const float*)d_in[18];
    const float* bout  = (const float*)d_in[19];

    int N = in_sizes[2];
    int E = in_sizes[3];

    char* base = (char*)d_ws;
    size_t off = 0;
    auto alloc = [&](size_t bytes) {
        char* p = base + off;
        off += (bytes + 255) & ~(size_t)255;
        return p;
    };
    uint32_t* h1    = (uint32_t*)alloc((size_t)N * 128 * 4);
    int*      rowptr= (int*)alloc((size_t)(N + 1) * 4);
    int*      cursor= (int*)alloc((size_t)N * 4);
    int*      bsum  = (int*)alloc(512 * 4);
    int*      csrc  = (int*)alloc((size_t)E * 4);
    float*    cwgt  = (float*)alloc((size_t)E * 4);
    ushort*   W1f   = (ushort*)alloc(32768 * 2);
    ushort*   W2f   = (ushort*)alloc(65536 * 2);
    ushort*   Wgf   = (ushort*)alloc(98304 * 2);
    float*    pooled= (float*)alloc(256 * 128 * 4);

    int eblk = (E + 255) / 256;
    int nblk1 = (N + 1023) / 1024;
    int cblk = (N + 63) / 64;

    hipMemsetAsync(cursor, 0, (size_t)N * sizeof(int), stream);
    hipMemsetAsync(pooled, 0, (size_t)256 * 128 * sizeof(float), stream);

    prep_weights_kernel<<<768, 256, 0, stream>>>(Wrel1, Wroot1, Wrel2, Wroot2,
                                                 Wsig, Wtanh, W1f, W2f, Wgf);

    // ---- CSR build ----
    hist_kernel<<<eblk, 256, 0, stream>>>(ei, cursor, E);
    scan1_kernel<<<nblk1, 256, 0, stream>>>(cursor, rowptr, bsum, N);
    scan2_kernel<<<1, 512, 0, stream>>>(bsum, nblk1);
    scan3_kernel<<<(N + 255) / 256, 256, 0, stream>>>(rowptr, bsum, N, E);
    hipMemcpyAsync(cursor, rowptr, (size_t)N * sizeof(int),
                   hipMemcpyDeviceToDevice, stream);
    fill_kernel<<<eblk, 256, 0, stream>>>(ei, ea, cursor, csrc, cwgt, E);

    // ---- fused conv1 (gather + GEMM) ----
    conv1_fused_kernel<<<cblk, 256, 0, stream>>>(x, rowptr, csrc, cwgt,
                                                 W1f, brel1, h1, N);

    // ---- fused conv2 + gate + pool (gather + 2 GEMMs) ----
    conv2_gate_kernel<<<cblk, 256, 0, stream>>>(h1, x, rowptr, csrc, cwgt,
                                                W2f, brel2, Wgf, bsig, btanh,
                                                batch, pooled, N);

    // ---- final MLP ----
    mlp_kernel<<<256, 256, 0, stream>>>(pooled, Wf1, bf1, Wf2, bf2, Wout, bout,
                                        (float*)d_out);
}

// Round 6
// 468.362 us; speedup vs baseline: 3.0645x; 1.1916x over previous
//
#include <hip/hip_runtime.h>
#include <cstdint>

#define RELU_COEF 0.05f
#define LEAKY(v) ((v) > 0.f ? (v) : RELU_COEF * (v))

typedef __attribute__((ext_vector_type(8))) short short8;
typedef __attribute__((ext_vector_type(4))) float f32x4;

#define MFMA(acc, a, b) \
    acc = __builtin_amdgcn_mfma_f32_16x16x32_bf16(a, b, acc, 0, 0, 0)

__device__ inline ushort f2bf(float f) {
    union { float f; uint32_t u; } v; v.f = f;
    return (ushort)((v.u + 0x7FFFu + ((v.u >> 16) & 1u)) >> 16);
}
__device__ inline float bf2f(ushort h) {
    union { uint32_t u; float f; } v; v.u = ((uint32_t)h) << 16;
    return v.f;
}
__device__ inline void split8(const float* p, short8& h8, short8& l8) {
    float4 a = *(const float4*)p;
    float4 b = *(const float4*)(p + 4);
    float v[8] = {a.x, a.y, a.z, a.w, b.x, b.y, b.z, b.w};
    short8 hh, ll;
#pragma unroll
    for (int i = 0; i < 8; ++i) {
        ushort hi = f2bf(v[i]);
        hh[i] = (short)hi;
        ll[i] = (short)f2bf(v[i] - bf2f(hi));
    }
    h8 = hh; l8 = ll;
}

// ---------------------------------------------------------------------------
// CSR build
// ---------------------------------------------------------------------------
__global__ __launch_bounds__(256) void hist_kernel(
    const int* __restrict__ ei, int* __restrict__ deg, int E)
{
    int e = blockIdx.x * 256 + threadIdx.x;
    if (e >= E) return;
    atomicAdd(&deg[ei[(size_t)E + e]], 1);
}

__global__ __launch_bounds__(256) void scan1_kernel(
    const int* __restrict__ in, int* __restrict__ out, int* __restrict__ bsum, int N)
{
    __shared__ int ts[256];
    int tid = threadIdx.x;
    int base = blockIdx.x * 1024 + tid * 4;
    int v[4];
    int s = 0;
#pragma unroll
    for (int j = 0; j < 4; ++j) {
        int idx = base + j;
        v[j] = (idx < N) ? in[idx] : 0;
        s += v[j];
    }
    ts[tid] = s;
    __syncthreads();
    for (int off = 1; off < 256; off <<= 1) {
        int t = (tid >= off) ? ts[tid - off] : 0;
        __syncthreads();
        ts[tid] += t;
        __syncthreads();
    }
    int excl = ts[tid] - s;
    if (tid == 255) bsum[blockIdx.x] = ts[255];
    int run = excl;
#pragma unroll
    for (int j = 0; j < 4; ++j) {
        int idx = base + j;
        if (idx < N) out[idx] = run;
        run += v[j];
    }
}

__global__ __launch_bounds__(512) void scan2_kernel(int* bsum, int nb)
{
    __shared__ int ts[512];
    int tid = threadIdx.x;
    int v = (tid < nb) ? bsum[tid] : 0;
    ts[tid] = v;
    __syncthreads();
    for (int off = 1; off < 512; off <<= 1) {
        int t = (tid >= off) ? ts[tid - off] : 0;
        __syncthreads();
        ts[tid] += t;
        __syncthreads();
    }
    if (tid < nb) bsum[tid] = ts[tid] - v;
}

__global__ __launch_bounds__(256) void scan3_kernel(
    int* __restrict__ rowptr, const int* __restrict__ bsum, int N, int E)
{
    int idx = blockIdx.x * 256 + threadIdx.x;
    if (idx < N) rowptr[idx] += bsum[idx >> 10];
    if (idx == 0) rowptr[N] = E;
}

__global__ __launch_bounds__(256) void fill_kernel(
    const int* __restrict__ ei, const float* __restrict__ ea,
    int* __restrict__ cursor, int* __restrict__ csrc, float* __restrict__ cw, int E)
{
    int e = blockIdx.x * 256 + threadIdx.x;
    if (e >= E) return;
    int t = ei[(size_t)E + e];
    int pos = atomicAdd(&cursor[t], 1);
    csrc[pos] = ei[e];
    cw[pos] = ea[e];
}

// ---------------------------------------------------------------------------
// x -> bf16 copy (gather payload for conv1)
// ---------------------------------------------------------------------------
__global__ __launch_bounds__(256) void xbf_kernel(
    const float* __restrict__ x, ushort* __restrict__ xbf, int total4)
{
    int i = blockIdx.x * 256 + threadIdx.x;
    if (i >= total4) return;
    float4 v = *(const float4*)(x + (size_t)i * 4);
    ushort4 h;
    h.x = f2bf(v.x); h.y = f2bf(v.y); h.z = f2bf(v.z); h.w = f2bf(v.w);
    *(ushort4*)(xbf + (size_t)i * 4) = h;
}

// ---------------------------------------------------------------------------
// Weight prep -> fragment-major split-bf16 layouts (coalesced B loads):
// W1f[kk:4][hl:2][kc:4][n:128][e:8]   (K=128: agg1|x)
// W2f[kk:8][hl:2][kc:4][n:128][e:8]   (K=256: agg2|h1)
// Wgf[kk:6][p:4 (sH,sL,tH,tL)][kc:4][n:128][e:8]  (K=192: h2|x)
// ---------------------------------------------------------------------------
__global__ __launch_bounds__(256) void prep_weights_kernel(
    const float* __restrict__ Wrel1, const float* __restrict__ Wroot1,
    const float* __restrict__ Wrel2, const float* __restrict__ Wroot2,
    const float* __restrict__ Wsig, const float* __restrict__ Wtanh,
    ushort* __restrict__ W1f, ushort* __restrict__ W2f, ushort* __restrict__ Wgf)
{
    int gid = blockIdx.x * 256 + threadIdx.x;
    if (gid < 32768) {
        int e = gid & 7, nn = (gid >> 3) & 127, kc = (gid >> 10) & 3;
        int hl = (gid >> 12) & 1, kk = gid >> 13;
        int k = kk * 32 + kc * 8 + e;
        float v = (k < 64) ? Wrel1[(size_t)k * 128 + nn]
                           : Wroot1[(size_t)(k - 64) * 128 + nn];
        ushort hi = f2bf(v);
        W1f[gid] = hl ? f2bf(v - bf2f(hi)) : hi;
        return;
    }
    int g2 = gid - 32768;
    if (g2 < 65536) {
        int e = g2 & 7, nn = (g2 >> 3) & 127, kc = (g2 >> 10) & 3;
        int hl = (g2 >> 12) & 1, kk = g2 >> 13;
        int k = kk * 32 + kc * 8 + e;
        float v = (k < 128) ? Wrel2[(size_t)k * 128 + nn]
                            : Wroot2[(size_t)(k - 128) * 128 + nn];
        ushort hi = f2bf(v);
        W2f[g2] = hl ? f2bf(v - bf2f(hi)) : hi;
        return;
    }
    int g3 = g2 - 65536;
    if (g3 < 98304) {
        int e = g3 & 7, nn = (g3 >> 3) & 127, kc = (g3 >> 10) & 3;
        int p = (g3 >> 12) & 3, kk = g3 >> 14;
        int k = kk * 32 + kc * 8 + e;
        float v = (p < 2) ? Wsig[(size_t)k * 128 + nn]
                          : Wtanh[(size_t)k * 128 + nn];
        ushort hi = f2bf(v);
        Wgf[g3] = (p & 1) ? f2bf(v - bf2f(hi)) : hi;
    }
}

// ---------------------------------------------------------------------------
// Fused conv1: gather(xbf) -> LDS planes; h1bf = bf16(leaky([agg1|x]@W1 + b))
// ---------------------------------------------------------------------------
__global__ __launch_bounds__(256) void conv1_fused_kernel(
    const float* __restrict__ x, const ushort* __restrict__ xbf,
    const int* __restrict__ rowptr,
    const int* __restrict__ csrc, const float* __restrict__ cw,
    const ushort* __restrict__ W1f, const float* __restrict__ brel,
    ushort* __restrict__ h1bf, int n)
{
    __shared__ __align__(16) ushort AH[64 * 72];
    __shared__ __align__(16) ushort AL[64 * 72];

    int tid = threadIdx.x;
    int lane = tid & 63;
    int wv = tid >> 6;
    int mr = lane & 15;
    int kc = lane >> 4;          // 0..3
    int i0 = blockIdx.x * 64;

    // ---- gather phase: 16 lanes/node, bf16 rows (128B), 8-deep loads ----
    {
        int q = tid & 15;
        int g = tid >> 4;
#pragma unroll
        for (int it = 0; it < 4; ++it) {
            int rl = it * 16 + g;
            int node = i0 + rl;
            float ax = 0.f, ay = 0.f, az = 0.f, aw = 0.f;
            if (node < n) {
                int b = rowptr[node], e = rowptr[node + 1];
                for (int cb = b; cb < e; cb += 16) {
                    int cnt = e - cb; if (cnt > 16) cnt = 16;
                    int sIdx = 0; float sW = 0.f;
                    if (q < cnt) { sIdx = csrc[cb + q]; sW = cw[cb + q]; }
                    int j = 0;
                    for (; j + 8 <= cnt; j += 8) {
                        int si[8]; float wi[8]; ushort4 fv[8];
#pragma unroll
                        for (int u = 0; u < 8; ++u) {
                            si[u] = __shfl(sIdx, j + u, 16);
                            wi[u] = __shfl(sW, j + u, 16);
                        }
#pragma unroll
                        for (int u = 0; u < 8; ++u)
                            fv[u] = *(const ushort4*)(xbf + (size_t)si[u] * 64 + q * 4);
#pragma unroll
                        for (int u = 0; u < 8; ++u) {
                            ax += wi[u] * bf2f(fv[u].x);
                            ay += wi[u] * bf2f(fv[u].y);
                            az += wi[u] * bf2f(fv[u].z);
                            aw += wi[u] * bf2f(fv[u].w);
                        }
                    }
                    for (; j < cnt; ++j) {
                        int s0 = __shfl(sIdx, j, 16); float w0 = __shfl(sW, j, 16);
                        ushort4 f0 = *(const ushort4*)(xbf + (size_t)s0 * 64 + q * 4);
                        ax += w0 * bf2f(f0.x); ay += w0 * bf2f(f0.y);
                        az += w0 * bf2f(f0.z); aw += w0 * bf2f(f0.w);
                    }
                }
            }
            ushort4 hh, ll;
            hh.x = f2bf(ax); ll.x = f2bf(ax - bf2f(hh.x));
            hh.y = f2bf(ay); ll.y = f2bf(ay - bf2f(hh.y));
            hh.z = f2bf(az); ll.z = f2bf(az - bf2f(hh.z));
            hh.w = f2bf(aw); ll.w = f2bf(aw - bf2f(hh.w));
            *(ushort4*)&AH[rl * 72 + q * 4] = hh;
            *(ushort4*)&AL[rl * 72 + q * 4] = ll;
        }
    }
    __syncthreads();

    // ---- GEMM ----
    int t0 = wv * 2;
    const ushort* Wp = W1f + kc * 1024 + t0 * 128 + mr * 8;
    f32x4 acc[4][2] = {};

#pragma unroll
    for (int kk = 0; kk < 2; ++kk) {      // A from LDS agg1 (K 0..63)
        short8 bH0 = *(const short8*)(Wp + kk * 8192);
        short8 bH1 = *(const short8*)(Wp + kk * 8192 + 128);
        short8 bL0 = *(const short8*)(Wp + kk * 8192 + 4096);
        short8 bL1 = *(const short8*)(Wp + kk * 8192 + 4096 + 128);
#pragma unroll
        for (int sub = 0; sub < 4; ++sub) {
            short8 aH = *(const short8*)&AH[(sub * 16 + mr) * 72 + kk * 32 + kc * 8];
            short8 aL = *(const short8*)&AL[(sub * 16 + mr) * 72 + kk * 32 + kc * 8];
            MFMA(acc[sub][0], aH, bH0); MFMA(acc[sub][0], aH, bL0); MFMA(acc[sub][0], aL, bH0);
            MFMA(acc[sub][1], aH, bH1); MFMA(acc[sub][1], aH, bL1); MFMA(acc[sub][1], aL, bH1);
        }
    }
#pragma unroll
    for (int kk = 2; kk < 4; ++kk) {      // A from x (K 64..127), exact split
        short8 bH0 = *(const short8*)(Wp + kk * 8192);
        short8 bH1 = *(const short8*)(Wp + kk * 8192 + 128);
        short8 bL0 = *(const short8*)(Wp + kk * 8192 + 4096);
        short8 bL1 = *(const short8*)(Wp + kk * 8192 + 4096 + 128);
#pragma unroll
        for (int sub = 0; sub < 4; ++sub) {
            int row = i0 + sub * 16 + mr; if (row > n - 1) row = n - 1;
            short8 aH, aL;
            split8(x + (size_t)row * 64 + (kk - 2) * 32 + kc * 8, aH, aL);
            MFMA(acc[sub][0], aH, bH0); MFMA(acc[sub][0], aH, bL0); MFMA(acc[sub][0], aL, bH0);
            MFMA(acc[sub][1], aH, bH1); MFMA(acc[sub][1], aH, bL1); MFMA(acc[sub][1], aL, bH1);
        }
    }

#pragma unroll
    for (int tt = 0; tt < 2; ++tt) {
        int c = (t0 + tt) * 16 + mr;
        float bv = brel[c];
#pragma unroll
        for (int sub = 0; sub < 4; ++sub)
#pragma unroll
            for (int j = 0; j < 4; ++j) {
                int r = i0 + sub * 16 + kc * 4 + j;
                if (r < n)
                    h1bf[(size_t)r * 128 + c] = f2bf(LEAKY(acc[sub][tt][j] + bv));
            }
    }
}

// ---------------------------------------------------------------------------
// Fused conv2 + gate + pool (bf16 h1 gather + 2 GEMMs + pooling)
// ---------------------------------------------------------------------------
__global__ __launch_bounds__(256) void conv2_gate_kernel(
    const ushort* __restrict__ h1bf, const float* __restrict__ x,
    const int* __restrict__ rowptr, const int* __restrict__ csrc,
    const float* __restrict__ cw,
    const ushort* __restrict__ W2f, const float* __restrict__ brel,
    const ushort* __restrict__ Wgf, const float* __restrict__ bsig,
    const float* __restrict__ btanh, const int* __restrict__ batch,
    float* __restrict__ pooled, int n)
{
    __shared__ __align__(16) ushort AH[64 * 136];   // agg2H -> h2H
    __shared__ __align__(16) ushort AL[64 * 136];   // agg2L -> h2L
    __shared__ int bS[64];
    float* gs = (float*)AH;                          // 32KB alias (after barrier)

    int tid = threadIdx.x;
    int lane = tid & 63;
    int wv = tid >> 6;
    int mr = lane & 15;
    int kc = lane >> 4;
    int i0 = blockIdx.x * 64;

    // ---- gather phase: 32 lanes/node, bf16 rows (256B), 8-deep loads ----
    {
        int q = tid & 31;
        int g = tid >> 5;
#pragma unroll
        for (int it = 0; it < 8; ++it) {
            int rl = it * 8 + g;
            int node = i0 + rl;
            float ax = 0.f, ay = 0.f, az = 0.f, aw = 0.f;
            if (node < n) {
                int b = rowptr[node], e = rowptr[node + 1];
                for (int cb = b; cb < e; cb += 32) {
                    int cnt = e - cb; if (cnt > 32) cnt = 32;
                    int sIdx = 0; float sW = 0.f;
                    if (q < cnt) { sIdx = csrc[cb + q]; sW = cw[cb + q]; }
                    int j = 0;
                    for (; j + 8 <= cnt; j += 8) {
                        int si[8]; float wi[8]; ushort4 fv[8];
#pragma unroll
                        for (int u = 0; u < 8; ++u) {
                            si[u] = __shfl(sIdx, j + u, 32);
                            wi[u] = __shfl(sW, j + u, 32);
                        }
#pragma unroll
                        for (int u = 0; u < 8; ++u)
                            fv[u] = *(const ushort4*)(h1bf + (size_t)si[u] * 128 + q * 4);
#pragma unroll
                        for (int u = 0; u < 8; ++u) {
                            ax += wi[u] * bf2f(fv[u].x);
                            ay += wi[u] * bf2f(fv[u].y);
                            az += wi[u] * bf2f(fv[u].z);
                            aw += wi[u] * bf2f(fv[u].w);
                        }
                    }
                    for (; j < cnt; ++j) {
                        int s0 = __shfl(sIdx, j, 32); float w0 = __shfl(sW, j, 32);
                        ushort4 f0 = *(const ushort4*)(h1bf + (size_t)s0 * 128 + q * 4);
                        ax += w0 * bf2f(f0.x); ay += w0 * bf2f(f0.y);
                        az += w0 * bf2f(f0.z); aw += w0 * bf2f(f0.w);
                    }
                }
            }
            ushort4 hh, ll;
            hh.x = f2bf(ax); ll.x = f2bf(ax - bf2f(hh.x));
            hh.y = f2bf(ay); ll.y = f2bf(ay - bf2f(hh.y));
            hh.z = f2bf(az); ll.z = f2bf(az - bf2f(hh.z));
            hh.w = f2bf(aw); ll.w = f2bf(aw - bf2f(hh.w));
            *(ushort4*)&AH[rl * 136 + q * 4] = hh;
            *(ushort4*)&AL[rl * 136 + q * 4] = ll;
        }
    }
    if (tid < 64) {
        int r = i0 + tid;
        bS[tid] = (r < n) ? batch[r] : -1;
    }
    __syncthreads();

    int t0 = wv * 2;

    // ---- GEMM1: h2 = leaky([agg2|h1] @ W2 + brel) ----
    f32x4 acc[4][2] = {};
    {
        const ushort* Wp = W2f + kc * 1024 + t0 * 128 + mr * 8;
#pragma unroll
        for (int kk = 0; kk < 4; ++kk) {           // A = LDS agg2 (K 0..127), split
            short8 bH0 = *(const short8*)(Wp + kk * 8192);
            short8 bH1 = *(const short8*)(Wp + kk * 8192 + 128);
            short8 bL0 = *(const short8*)(Wp + kk * 8192 + 4096);
            short8 bL1 = *(const short8*)(Wp + kk * 8192 + 4096 + 128);
#pragma unroll
            for (int sub = 0; sub < 4; ++sub) {
                short8 aH = *(const short8*)&AH[(sub * 16 + mr) * 136 + kk * 32 + kc * 8];
                short8 aL = *(const short8*)&AL[(sub * 16 + mr) * 136 + kk * 32 + kc * 8];
                MFMA(acc[sub][0], aH, bH0); MFMA(acc[sub][0], aH, bL0); MFMA(acc[sub][0], aL, bH0);
                MFMA(acc[sub][1], aH, bH1); MFMA(acc[sub][1], aH, bL1); MFMA(acc[sub][1], aL, bH1);
            }
        }
#pragma unroll
        for (int kk = 4; kk < 8; ++kk) {           // A = h1bf global (K 128..255)
            short8 bH0 = *(const short8*)(Wp + kk * 8192);
            short8 bH1 = *(const short8*)(Wp + kk * 8192 + 128);
            short8 bL0 = *(const short8*)(Wp + kk * 8192 + 4096);
            short8 bL1 = *(const short8*)(Wp + kk * 8192 + 4096 + 128);
#pragma unroll
            for (int sub = 0; sub < 4; ++sub) {
                int row = i0 + sub * 16 + mr; if (row > n - 1) row = n - 1;
                short8 aH = *(const short8*)(h1bf + (size_t)row * 128 + (kk - 4) * 32 + kc * 8);
                MFMA(acc[sub][0], aH, bH0); MFMA(acc[sub][0], aH, bL0);
                MFMA(acc[sub][1], aH, bH1); MFMA(acc[sub][1], aH, bL1);
            }
        }
    }
    __syncthreads();   // agg2 LDS reads complete -> safe to overwrite with h2

#pragma unroll
    for (int tt = 0; tt < 2; ++tt) {
        int c = (t0 + tt) * 16 + mr;
        float bv = brel[c];
#pragma unroll
        for (int sub = 0; sub < 4; ++sub)
#pragma unroll
            for (int j = 0; j < 4; ++j) {
                int rl = sub * 16 + kc * 4 + j;
                float v = LEAKY(acc[sub][tt][j] + bv);
                ushort hi = f2bf(v);
                AH[rl * 136 + c] = hi;
                AL[rl * 136 + c] = f2bf(v - bf2f(hi));
            }
    }
    __syncthreads();

    // ---- GEMM2: gate over [h2|x] ----
    f32x4 as[4][2] = {}, at_[4][2] = {};
    {
        const ushort* Wp = Wgf + kc * 1024 + t0 * 128 + mr * 8;
#pragma unroll
        for (int kk = 0; kk < 4; ++kk) {           // A = LDS h2 (K 0..127)
            short8 sH0 = *(const short8*)(Wp + kk * 16384);
            short8 sH1 = *(const short8*)(Wp + kk * 16384 + 128);
            short8 sL0 = *(const short8*)(Wp + kk * 16384 + 4096);
            short8 sL1 = *(const short8*)(Wp + kk * 16384 + 4096 + 128);
            short8 tH0 = *(const short8*)(Wp + kk * 16384 + 8192);
            short8 tH1 = *(const short8*)(Wp + kk * 16384 + 8192 + 128);
            short8 tL0 = *(const short8*)(Wp + kk * 16384 + 12288);
            short8 tL1 = *(const short8*)(Wp + kk * 16384 + 12288 + 128);
#pragma unroll
            for (int sub = 0; sub < 4; ++sub) {
                short8 aH = *(const short8*)&AH[(sub * 16 + mr) * 136 + kk * 32 + kc * 8];
                short8 aL = *(const short8*)&AL[(sub * 16 + mr) * 136 + kk * 32 + kc * 8];
                MFMA(as[sub][0], aH, sH0); MFMA(as[sub][0], aH, sL0); MFMA(as[sub][0], aL, sH0);
                MFMA(as[sub][1], aH, sH1); MFMA(as[sub][1], aH, sL1); MFMA(as[sub][1], aL, sH1);
                MFMA(at_[sub][0], aH, tH0); MFMA(at_[sub][0], aH, tL0); MFMA(at_[sub][0], aL, tH0);
                MFMA(at_[sub][1], aH, tH1); MFMA(at_[sub][1], aH, tL1); MFMA(at_[sub][1], aL, tH1);
            }
        }
#pragma unroll
        for (int kk = 4; kk < 6; ++kk) {           // A = x (K 128..191), exact split
            short8 sH0 = *(const short8*)(Wp + kk * 16384);
            short8 sH1 = *(const short8*)(Wp + kk * 16384 + 128);
            short8 sL0 = *(const short8*)(Wp + kk * 16384 + 4096);
            short8 sL1 = *(const short8*)(Wp + kk * 16384 + 4096 + 128);
            short8 tH0 = *(const short8*)(Wp + kk * 16384 + 8192);
            short8 tH1 = *(const short8*)(Wp + kk * 16384 + 8192 + 128);
            short8 tL0 = *(const short8*)(Wp + kk * 16384 + 12288);
            short8 tL1 = *(const short8*)(Wp + kk * 16384 + 12288 + 128);
#pragma unroll
            for (int sub = 0; sub < 4; ++sub) {
                int row = i0 + sub * 16 + mr; if (row > n - 1) row = n - 1;
                short8 aH, aL;
                split8(x + (size_t)row * 64 + (kk - 4) * 32 + kc * 8, aH, aL);
                MFMA(as[sub][0], aH, sH0); MFMA(as[sub][0], aH, sL0); MFMA(as[sub][0], aL, sH0);
                MFMA(as[sub][1], aH, sH1); MFMA(as[sub][1], aH, sL1); MFMA(as[sub][1], aL, sH1);
                MFMA(at_[sub][0], aH, tH0); MFMA(at_[sub][0], aH, tL0); MFMA(at_[sub][0], aL, tH0);
                MFMA(at_[sub][1], aH, tH1); MFMA(at_[sub][1], aH, tL1); MFMA(at_[sub][1], aL, tH1);
            }
        }
    }
    __syncthreads();   // h2 LDS reads complete -> safe to alias gs

    // ---- gate epilogue ----
#pragma unroll
    for (int tt = 0; tt < 2; ++tt) {
        int c = (t0 + tt) * 16 + mr;
        float bsv = bsig[c], btv = btanh[c];
#pragma unroll
        for (int sub = 0; sub < 4; ++sub)
#pragma unroll
            for (int j = 0; j < 4; ++j) {
                int rl = sub * 16 + kc * 4 + j;
                float s = as[sub][tt][j] + bsv;
                s = fminf(fmaxf(s, -30.f), 30.f);
                float ta = at_[sub][tt][j] + btv;
                ta = fminf(fmaxf(ta, -15.f), 15.f);
                float e2 = __expf(2.f * ta);
                float th = (e2 - 1.f) / (e2 + 1.f);
                gs[rl * 128 + c] = th / (1.f + __expf(s));
            }
    }
    __syncthreads();

    // ---- run-compressed pooling ----
    int j = tid & 127;
    int m0 = (tid >> 7) * 32;
    float acc2 = 0.f;
    int cur = -1;
    for (int m = m0; m < m0 + 32; ++m) {
        int b = bS[m];
        if (b < 0) break;
        if (b != cur) {
            if (cur >= 0) atomicAdd(&pooled[(size_t)cur * 128 + j], acc2);
            cur = b;
            acc2 = 0.f;
        }
        acc2 += gs[m * 128 + j];
    }
    if (cur >= 0) atomicAdd(&pooled[(size_t)cur * 128 + j], acc2);
}

// ---------------------------------------------------------------------------
// Final per-graph MLP
// ---------------------------------------------------------------------------
__global__ __launch_bounds__(256) void mlp_kernel(
    const float* __restrict__ pooled,
    const float* __restrict__ Wf1, const float* __restrict__ bf1,
    const float* __restrict__ Wf2, const float* __restrict__ bf2,
    const float* __restrict__ Wout, const float* __restrict__ bout,
    float* __restrict__ out)
{
    __shared__ float p[128];
    __shared__ float f1[128];
    __shared__ float f2[258];
    __shared__ float red[4];

    int g = blockIdx.x;
    int tid = threadIdx.x;

    if (tid < 128) p[tid] = pooled[(size_t)g * 128 + tid];
    __syncthreads();

    if (tid < 128) {
        float a = bf1[tid];
        for (int k = 0; k < 128; ++k) a += p[k] * Wf1[k * 128 + tid];
        f1[tid] = LEAKY(a);
    }
    __syncthreads();

    for (int j = tid; j < 258; j += 256) {
        float a = bf2[j];
        for (int k = 0; k < 128; ++k) a += f1[k] * Wf2[k * 258 + j];
        f2[j] = LEAKY(a);
    }
    __syncthreads();

    float a = 0.f;
    for (int j = tid; j < 258; j += 256) a += f2[j] * Wout[j];
#pragma unroll
    for (int off = 32; off > 0; off >>= 1) a += __shfl_down(a, off, 64);
    if ((tid & 63) == 0) red[tid >> 6] = a;
    __syncthreads();
    if (tid == 0) {
        float v = red[0] + red[1] + red[2] + red[3] + bout[0];
        out[g] = 1.f / (1.f + expf(-v));
    }
}

// ---------------------------------------------------------------------------
extern "C" void kernel_launch(void* const* d_in, const int* in_sizes, int n_in,
                              void* d_out, int out_size, void* d_ws, size_t ws_size,
                              hipStream_t stream)
{
    const float* x     = (const float*)d_in[0];
    const int*   ei    = (const int*)d_in[1];
    const int*   batch = (const int*)d_in[2];
    const float* ea    = (const float*)d_in[3];
    const float* Wrel1 = (const float*)d_in[4];
    const float* brel1 = (const float*)d_in[5];
    const float* Wroot1= (const float*)d_in[6];
    const float* Wrel2 = (const float*)d_in[7];
    const float* brel2 = (const float*)d_in[8];
    const float* Wroot2= (const float*)d_in[9];
    const float* Wsig  = (const float*)d_in[10];
    const float* bsig  = (const float*)d_in[11];
    const float* Wtanh = (const float*)d_in[12];
    const float* btanh = (const float*)d_in[13];
    const float* Wf1   = (const float*)d_in[14];
    const float* bf1   = (const float*)d_in[15];
    const float* Wf2   = (const float*)d_in[16];
    const float* bf2   = (const float*)d_in[17];
    const float* Wout  = (const float*)d_in[18];
    const float* bout  = (const float*)d_in[19];

    int N = in_sizes[2];
    int E = in_sizes[3];

    char* base = (char*)d_ws;
    size_t off = 0;
    auto alloc = [&](size_t bytes) {
        char* p = base + off;
        off += (bytes + 255) & ~(size_t)255;
        return p;
    };
    ushort*   h1bf  = (ushort*)alloc((size_t)N * 128 * 2);
    ushort*   xbf   = (ushort*)alloc((size_t)N * 64 * 2);
    int*      rowptr= (int*)alloc((size_t)(N + 1) * 4);
    int*      cursor= (int*)alloc((size_t)N * 4);
    int*      bsum  = (int*)alloc(512 * 4);
    int*      csrc  = (int*)alloc((size_t)E * 4);
    float*    cwgt  = (float*)alloc((size_t)E * 4);
    ushort*   W1f   = (ushort*)alloc(32768 * 2);
    ushort*   W2f   = (ushort*)alloc(65536 * 2);
    ushort*   Wgf   = (ushort*)alloc(98304 * 2);
    float*    pooled= (float*)alloc(256 * 128 * 4);

    int eblk = (E + 255) / 256;
    int nblk1 = (N + 1023) / 1024;
    int cblk = (N + 63) / 64;

    hipMemsetAsync(cursor, 0, (size_t)N * sizeof(int), stream);
    hipMemsetAsync(pooled, 0, (size_t)256 * 128 * sizeof(float), stream);

    prep_weights_kernel<<<768, 256, 0, stream>>>(Wrel1, Wroot1, Wrel2, Wroot2,
                                                 Wsig, Wtanh, W1f, W2f, Wgf);
    xbf_kernel<<<(N * 16 + 255) / 256, 256, 0, stream>>>(x, xbf, N * 16);

    // ---- CSR build ----
    hist_kernel<<<eblk, 256, 0, stream>>>(ei, cursor, E);
    scan1_kernel<<<nblk1, 256, 0, stream>>>(cursor, rowptr, bsum, N);
    scan2_kernel<<<1, 512, 0, stream>>>(bsum, nblk1);
    scan3_kernel<<<(N + 255) / 256, 256, 0, stream>>>(rowptr, bsum, N, E);
    hipMemcpyAsync(cursor, rowptr, (size_t)N * sizeof(int),
                   hipMemcpyDeviceToDevice, stream);
    fill_kernel<<<eblk, 256, 0, stream>>>(ei, ea, cursor, csrc, cwgt, E);

    // ---- fused conv1 (gather + GEMM) ----
    conv1_fused_kernel<<<cblk, 256, 0, stream>>>(x, xbf, rowptr, csrc, cwgt,
                                                 W1f, brel1, h1bf, N);

    // ---- fused conv2 + gate + pool (gather + 2 GEMMs) ----
    conv2_gate_kernel<<<cblk, 256, 0, stream>>>(h1bf, x, rowptr, csrc, cwgt,
                                                W2f, brel2, Wgf, bsig, btanh,
                                                batch, pooled, N);

    // ---- final MLP ----
    mlp_kernel<<<256, 256, 0, stream>>>(pooled, Wf1, bf1, Wf2, bf2, Wout, bout,
                                        (float*)d_out);
}

// Round 7
// 429.061 us; speedup vs baseline: 3.3452x; 1.0916x over previous
//
#include <hip/hip_runtime.h>
#include <cstdint>

#define RELU_COEF 0.05f
#define LEAKY(v) ((v) > 0.f ? (v) : RELU_COEF * (v))

typedef __attribute__((ext_vector_type(8))) short short8;
typedef __attribute__((ext_vector_type(4))) float f32x4;

#define MFMA(acc, a, b) \
    acc = __builtin_amdgcn_mfma_f32_16x16x32_bf16(a, b, acc, 0, 0, 0)

__device__ inline ushort f2bf(float f) {
    union { float f; uint32_t u; } v; v.f = f;
    return (ushort)((v.u + 0x7FFFu + ((v.u >> 16) & 1u)) >> 16);
}
__device__ inline float bf2f(ushort h) {
    union { uint32_t u; float f; } v; v.u = ((uint32_t)h) << 16;
    return v.f;
}
__device__ inline void split8(const float* p, short8& h8, short8& l8) {
    float4 a = *(const float4*)p;
    float4 b = *(const float4*)(p + 4);
    float v[8] = {a.x, a.y, a.z, a.w, b.x, b.y, b.z, b.w};
    short8 hh, ll;
#pragma unroll
    for (int i = 0; i < 8; ++i) {
        ushort hi = f2bf(v[i]);
        hh[i] = (short)hi;
        ll[i] = (short)f2bf(v[i] - bf2f(hi));
    }
    h8 = hh; l8 = ll;
}

// ---------------------------------------------------------------------------
// CSR build
// ---------------------------------------------------------------------------
__global__ __launch_bounds__(256) void hist_kernel(
    const int* __restrict__ ei, int* __restrict__ deg, int E)
{
    int e = blockIdx.x * 256 + threadIdx.x;
    if (e >= E) return;
    atomicAdd(&deg[ei[(size_t)E + e]], 1);
}

__global__ __launch_bounds__(256) void scan1_kernel(
    const int* __restrict__ in, int* __restrict__ out, int* __restrict__ bsum, int N)
{
    __shared__ int ts[256];
    int tid = threadIdx.x;
    int base = blockIdx.x * 1024 + tid * 4;
    int v[4];
    int s = 0;
#pragma unroll
    for (int j = 0; j < 4; ++j) {
        int idx = base + j;
        v[j] = (idx < N) ? in[idx] : 0;
        s += v[j];
    }
    ts[tid] = s;
    __syncthreads();
    for (int off = 1; off < 256; off <<= 1) {
        int t = (tid >= off) ? ts[tid - off] : 0;
        __syncthreads();
        ts[tid] += t;
        __syncthreads();
    }
    int excl = ts[tid] - s;
    if (tid == 255) bsum[blockIdx.x] = ts[255];
    int run = excl;
#pragma unroll
    for (int j = 0; j < 4; ++j) {
        int idx = base + j;
        if (idx < N) out[idx] = run;
        run += v[j];
    }
}

__global__ __launch_bounds__(512) void scan2_kernel(int* bsum, int nb)
{
    __shared__ int ts[512];
    int tid = threadIdx.x;
    int v = (tid < nb) ? bsum[tid] : 0;
    ts[tid] = v;
    __syncthreads();
    for (int off = 1; off < 512; off <<= 1) {
        int t = (tid >= off) ? ts[tid - off] : 0;
        __syncthreads();
        ts[tid] += t;
        __syncthreads();
    }
    if (tid < nb) bsum[tid] = ts[tid] - v;
}

__global__ __launch_bounds__(256) void scan3_kernel(
    int* __restrict__ rowptr, const int* __restrict__ bsum, int N, int E)
{
    int idx = blockIdx.x * 256 + threadIdx.x;
    if (idx < N) rowptr[idx] += bsum[idx >> 10];
    if (idx == 0) rowptr[N] = E;
}

__global__ __launch_bounds__(256) void fill_kernel(
    const int* __restrict__ ei, const float* __restrict__ ea,
    int* __restrict__ cursor, int* __restrict__ csrc, float* __restrict__ cw, int E)
{
    int e = blockIdx.x * 256 + threadIdx.x;
    if (e >= E) return;
    int t = ei[(size_t)E + e];
    int pos = atomicAdd(&cursor[t], 1);
    csrc[pos] = ei[e];
    cw[pos] = ea[e];
}

// ---------------------------------------------------------------------------
// x -> bf16 copy (gather payload for conv1)
// ---------------------------------------------------------------------------
__global__ __launch_bounds__(256) void xbf_kernel(
    const float* __restrict__ x, ushort* __restrict__ xbf, int total4)
{
    int i = blockIdx.x * 256 + threadIdx.x;
    if (i >= total4) return;
    float4 v = *(const float4*)(x + (size_t)i * 4);
    ushort4 h;
    h.x = f2bf(v.x); h.y = f2bf(v.y); h.z = f2bf(v.z); h.w = f2bf(v.w);
    *(ushort4*)(xbf + (size_t)i * 4) = h;
}

// ---------------------------------------------------------------------------
// Weight prep -> fragment-major split-bf16 layouts (coalesced B loads):
// W1f[kk:4][hl:2][kc:4][n:128][e:8]   (K=128: agg1|x)
// W2f[kk:8][hl:2][kc:4][n:128][e:8]   (K=256: agg2|h1)
// Wgf[kk:6][p:4 (sH,sL,tH,tL)][kc:4][n:128][e:8]  (K=192: h2|x)
// ---------------------------------------------------------------------------
__global__ __launch_bounds__(256) void prep_weights_kernel(
    const float* __restrict__ Wrel1, const float* __restrict__ Wroot1,
    const float* __restrict__ Wrel2, const float* __restrict__ Wroot2,
    const float* __restrict__ Wsig, const float* __restrict__ Wtanh,
    ushort* __restrict__ W1f, ushort* __restrict__ W2f, ushort* __restrict__ Wgf)
{
    int gid = blockIdx.x * 256 + threadIdx.x;
    if (gid < 32768) {
        int e = gid & 7, nn = (gid >> 3) & 127, kc = (gid >> 10) & 3;
        int hl = (gid >> 12) & 1, kk = gid >> 13;
        int k = kk * 32 + kc * 8 + e;
        float v = (k < 64) ? Wrel1[(size_t)k * 128 + nn]
                           : Wroot1[(size_t)(k - 64) * 128 + nn];
        ushort hi = f2bf(v);
        W1f[gid] = hl ? f2bf(v - bf2f(hi)) : hi;
        return;
    }
    int g2 = gid - 32768;
    if (g2 < 65536) {
        int e = g2 & 7, nn = (g2 >> 3) & 127, kc = (g2 >> 10) & 3;
        int hl = (g2 >> 12) & 1, kk = g2 >> 13;
        int k = kk * 32 + kc * 8 + e;
        float v = (k < 128) ? Wrel2[(size_t)k * 128 + nn]
                            : Wroot2[(size_t)(k - 128) * 128 + nn];
        ushort hi = f2bf(v);
        W2f[g2] = hl ? f2bf(v - bf2f(hi)) : hi;
        return;
    }
    int g3 = g2 - 65536;
    if (g3 < 98304) {
        int e = g3 & 7, nn = (g3 >> 3) & 127, kc = (g3 >> 10) & 3;
        int p = (g3 >> 12) & 3, kk = g3 >> 14;
        int k = kk * 32 + kc * 8 + e;
        float v = (p < 2) ? Wsig[(size_t)k * 128 + nn]
                          : Wtanh[(size_t)k * 128 + nn];
        ushort hi = f2bf(v);
        Wgf[g3] = (p & 1) ? f2bf(v - bf2f(hi)) : hi;
    }
}

// ---------------------------------------------------------------------------
// Fused conv1 (32-row tile, f32 LDS agg): h1bf = bf16(leaky([agg1|x]@W1 + b))
// ---------------------------------------------------------------------------
__global__ __launch_bounds__(256) void conv1_fused_kernel(
    const float* __restrict__ x, const ushort* __restrict__ xbf,
    const int* __restrict__ rowptr,
    const int* __restrict__ csrc, const float* __restrict__ cw,
    const ushort* __restrict__ W1f, const float* __restrict__ brel,
    ushort* __restrict__ h1bf, int n)
{
    __shared__ __align__(16) float agg[32 * 68];   // 8704 B

    int tid = threadIdx.x;
    int lane = tid & 63;
    int wv = tid >> 6;
    int mr = lane & 15;
    int kc = lane >> 4;          // 0..3
    int i0 = blockIdx.x * 32;

    // ---- gather phase: 16 lanes/node, 16 groups, 2 iters ----
    {
        int q = tid & 15;
        int g = tid >> 4;
#pragma unroll
        for (int it = 0; it < 2; ++it) {
            int rl = it * 16 + g;
            int node = i0 + rl;
            float ax = 0.f, ay = 0.f, az = 0.f, aw = 0.f;
            if (node < n) {
                int b = rowptr[node], e = rowptr[node + 1];
                for (int cb = b; cb < e; cb += 16) {
                    int cnt = e - cb; if (cnt > 16) cnt = 16;
                    int sIdx = 0; float sW = 0.f;
                    if (q < cnt) { sIdx = csrc[cb + q]; sW = cw[cb + q]; }
                    int j = 0;
                    for (; j + 8 <= cnt; j += 8) {
                        int si[8]; float wi[8]; ushort4 fv[8];
#pragma unroll
                        for (int u = 0; u < 8; ++u) {
                            si[u] = __shfl(sIdx, j + u, 16);
                            wi[u] = __shfl(sW, j + u, 16);
                        }
#pragma unroll
                        for (int u = 0; u < 8; ++u)
                            fv[u] = *(const ushort4*)(xbf + (size_t)si[u] * 64 + q * 4);
#pragma unroll
                        for (int u = 0; u < 8; ++u) {
                            ax += wi[u] * bf2f(fv[u].x);
                            ay += wi[u] * bf2f(fv[u].y);
                            az += wi[u] * bf2f(fv[u].z);
                            aw += wi[u] * bf2f(fv[u].w);
                        }
                    }
                    for (; j < cnt; ++j) {
                        int s0 = __shfl(sIdx, j, 16); float w0 = __shfl(sW, j, 16);
                        ushort4 f0 = *(const ushort4*)(xbf + (size_t)s0 * 64 + q * 4);
                        ax += w0 * bf2f(f0.x); ay += w0 * bf2f(f0.y);
                        az += w0 * bf2f(f0.z); aw += w0 * bf2f(f0.w);
                    }
                }
            }
            *(float4*)&agg[rl * 68 + q * 4] = make_float4(ax, ay, az, aw);
        }
    }
    __syncthreads();

    // ---- GEMM ----
    int t0 = wv * 2;
    const ushort* Wp = W1f + kc * 1024 + t0 * 128 + mr * 8;
    f32x4 acc[2][2] = {};

#pragma unroll
    for (int kk = 0; kk < 2; ++kk) {      // A from LDS agg (K 0..63), split on the fly
        short8 bH0 = *(const short8*)(Wp + kk * 8192);
        short8 bH1 = *(const short8*)(Wp + kk * 8192 + 128);
        short8 bL0 = *(const short8*)(Wp + kk * 8192 + 4096);
        short8 bL1 = *(const short8*)(Wp + kk * 8192 + 4096 + 128);
#pragma unroll
        for (int sub = 0; sub < 2; ++sub) {
            short8 aH, aL;
            split8(&agg[(sub * 16 + mr) * 68 + kk * 32 + kc * 8], aH, aL);
            MFMA(acc[sub][0], aH, bH0); MFMA(acc[sub][0], aH, bL0); MFMA(acc[sub][0], aL, bH0);
            MFMA(acc[sub][1], aH, bH1); MFMA(acc[sub][1], aH, bL1); MFMA(acc[sub][1], aL, bH1);
        }
    }
#pragma unroll
    for (int kk = 2; kk < 4; ++kk) {      // A from x (K 64..127), exact split
        short8 bH0 = *(const short8*)(Wp + kk * 8192);
        short8 bH1 = *(const short8*)(Wp + kk * 8192 + 128);
        short8 bL0 = *(const short8*)(Wp + kk * 8192 + 4096);
        short8 bL1 = *(const short8*)(Wp + kk * 8192 + 4096 + 128);
#pragma unroll
        for (int sub = 0; sub < 2; ++sub) {
            int row = i0 + sub * 16 + mr; if (row > n - 1) row = n - 1;
            short8 aH, aL;
            split8(x + (size_t)row * 64 + (kk - 2) * 32 + kc * 8, aH, aL);
            MFMA(acc[sub][0], aH, bH0); MFMA(acc[sub][0], aH, bL0); MFMA(acc[sub][0], aL, bH0);
            MFMA(acc[sub][1], aH, bH1); MFMA(acc[sub][1], aH, bL1); MFMA(acc[sub][1], aL, bH1);
        }
    }

#pragma unroll
    for (int tt = 0; tt < 2; ++tt) {
        int c = (t0 + tt) * 16 + mr;
        float bv = brel[c];
#pragma unroll
        for (int sub = 0; sub < 2; ++sub)
#pragma unroll
            for (int j = 0; j < 4; ++j) {
                int r = i0 + sub * 16 + kc * 4 + j;
                if (r < n)
                    h1bf[(size_t)r * 128 + c] = f2bf(LEAKY(acc[sub][tt][j] + bv));
            }
    }
}

// ---------------------------------------------------------------------------
// Fused conv2 + gate + pool (32-row tile, f32 LDS agg/h2, split on the fly)
// ---------------------------------------------------------------------------
__global__ __launch_bounds__(256) void conv2_gate_kernel(
    const ushort* __restrict__ h1bf, const float* __restrict__ x,
    const int* __restrict__ rowptr, const int* __restrict__ csrc,
    const float* __restrict__ cw,
    const ushort* __restrict__ W2f, const float* __restrict__ brel,
    const ushort* __restrict__ Wgf, const float* __restrict__ bsig,
    const float* __restrict__ btanh, const int* __restrict__ batch,
    float* __restrict__ pooled, int n)
{
    __shared__ __align__(16) float agg[32 * 132];   // 16896 B: agg2 -> h2 -> gs
    __shared__ int bS[32];
    float* gs = agg;                                 // alias (stride 128)

    int tid = threadIdx.x;
    int lane = tid & 63;
    int wv = tid >> 6;
    int mr = lane & 15;
    int kc = lane >> 4;
    int i0 = blockIdx.x * 32;

    // ---- gather phase: 32 lanes/node, 8 groups, 4 iters ----
    {
        int q = tid & 31;
        int g = tid >> 5;
#pragma unroll
        for (int it = 0; it < 4; ++it) {
            int rl = it * 8 + g;
            int node = i0 + rl;
            float ax = 0.f, ay = 0.f, az = 0.f, aw = 0.f;
            if (node < n) {
                int b = rowptr[node], e = rowptr[node + 1];
                for (int cb = b; cb < e; cb += 32) {
                    int cnt = e - cb; if (cnt > 32) cnt = 32;
                    int sIdx = 0; float sW = 0.f;
                    if (q < cnt) { sIdx = csrc[cb + q]; sW = cw[cb + q]; }
                    int j = 0;
                    for (; j + 8 <= cnt; j += 8) {
                        int si[8]; float wi[8]; ushort4 fv[8];
#pragma unroll
                        for (int u = 0; u < 8; ++u) {
                            si[u] = __shfl(sIdx, j + u, 32);
                            wi[u] = __shfl(sW, j + u, 32);
                        }
#pragma unroll
                        for (int u = 0; u < 8; ++u)
                            fv[u] = *(const ushort4*)(h1bf + (size_t)si[u] * 128 + q * 4);
#pragma unroll
                        for (int u = 0; u < 8; ++u) {
                            ax += wi[u] * bf2f(fv[u].x);
                            ay += wi[u] * bf2f(fv[u].y);
                            az += wi[u] * bf2f(fv[u].z);
                            aw += wi[u] * bf2f(fv[u].w);
                        }
                    }
                    for (; j < cnt; ++j) {
                        int s0 = __shfl(sIdx, j, 32); float w0 = __shfl(sW, j, 32);
                        ushort4 f0 = *(const ushort4*)(h1bf + (size_t)s0 * 128 + q * 4);
                        ax += w0 * bf2f(f0.x); ay += w0 * bf2f(f0.y);
                        az += w0 * bf2f(f0.z); aw += w0 * bf2f(f0.w);
                    }
                }
            }
            *(float4*)&agg[rl * 132 + q * 4] = make_float4(ax, ay, az, aw);
        }
    }
    if (tid < 32) {
        int r = i0 + tid;
        bS[tid] = (r < n) ? batch[r] : -1;
    }
    __syncthreads();

    int t0 = wv * 2;

    // ---- GEMM1: h2 = leaky([agg2|h1] @ W2 + brel) ----
    f32x4 acc[2][2] = {};
    {
        const ushort* Wp = W2f + kc * 1024 + t0 * 128 + mr * 8;
#pragma unroll
        for (int kk = 0; kk < 4; ++kk) {           // A = LDS agg f32 (K 0..127)
            short8 bH0 = *(const short8*)(Wp + kk * 8192);
            short8 bH1 = *(const short8*)(Wp + kk * 8192 + 128);
            short8 bL0 = *(const short8*)(Wp + kk * 8192 + 4096);
            short8 bL1 = *(const short8*)(Wp + kk * 8192 + 4096 + 128);
#pragma unroll
            for (int sub = 0; sub < 2; ++sub) {
                short8 aH, aL;
                split8(&agg[(sub * 16 + mr) * 132 + kk * 32 + kc * 8], aH, aL);
                MFMA(acc[sub][0], aH, bH0); MFMA(acc[sub][0], aH, bL0); MFMA(acc[sub][0], aL, bH0);
                MFMA(acc[sub][1], aH, bH1); MFMA(acc[sub][1], aH, bL1); MFMA(acc[sub][1], aL, bH1);
            }
        }
#pragma unroll
        for (int kk = 4; kk < 8; ++kk) {           // A = h1bf global (K 128..255)
            short8 bH0 = *(const short8*)(Wp + kk * 8192);
            short8 bH1 = *(const short8*)(Wp + kk * 8192 + 128);
            short8 bL0 = *(const short8*)(Wp + kk * 8192 + 4096);
            short8 bL1 = *(const short8*)(Wp + kk * 8192 + 4096 + 128);
#pragma unroll
            for (int sub = 0; sub < 2; ++sub) {
                int row = i0 + sub * 16 + mr; if (row > n - 1) row = n - 1;
                short8 aH = *(const short8*)(h1bf + (size_t)row * 128 + (kk - 4) * 32 + kc * 8);
                MFMA(acc[sub][0], aH, bH0); MFMA(acc[sub][0], aH, bL0);
                MFMA(acc[sub][1], aH, bH1); MFMA(acc[sub][1], aH, bL1);
            }
        }
    }
    __syncthreads();   // all agg reads complete -> safe to overwrite with h2

#pragma unroll
    for (int tt = 0; tt < 2; ++tt) {
        int c = (t0 + tt) * 16 + mr;
        float bv = brel[c];
#pragma unroll
        for (int sub = 0; sub < 2; ++sub)
#pragma unroll
            for (int j = 0; j < 4; ++j) {
                int rl = sub * 16 + kc * 4 + j;
                agg[rl * 132 + c] = LEAKY(acc[sub][tt][j] + bv);
            }
    }
    __syncthreads();

    // ---- GEMM2: gate over [h2|x] ----
    f32x4 as[2][2] = {}, at_[2][2] = {};
    {
        const ushort* Wp = Wgf + kc * 1024 + t0 * 128 + mr * 8;
#pragma unroll
        for (int kk = 0; kk < 4; ++kk) {           // A = LDS h2 f32 (K 0..127)
            short8 sH0 = *(const short8*)(Wp + kk * 16384);
            short8 sH1 = *(const short8*)(Wp + kk * 16384 + 128);
            short8 sL0 = *(const short8*)(Wp + kk * 16384 + 4096);
            short8 sL1 = *(const short8*)(Wp + kk * 16384 + 4096 + 128);
            short8 tH0 = *(const short8*)(Wp + kk * 16384 + 8192);
            short8 tH1 = *(const short8*)(Wp + kk * 16384 + 8192 + 128);
            short8 tL0 = *(const short8*)(Wp + kk * 16384 + 12288);
            short8 tL1 = *(const short8*)(Wp + kk * 16384 + 12288 + 128);
#pragma unroll
            for (int sub = 0; sub < 2; ++sub) {
                short8 aH, aL;
                split8(&agg[(sub * 16 + mr) * 132 + kk * 32 + kc * 8], aH, aL);
                MFMA(as[sub][0], aH, sH0); MFMA(as[sub][0], aH, sL0); MFMA(as[sub][0], aL, sH0);
                MFMA(as[sub][1], aH, sH1); MFMA(as[sub][1], aH, sL1); MFMA(as[sub][1], aL, sH1);
                MFMA(at_[sub][0], aH, tH0); MFMA(at_[sub][0], aH, tL0); MFMA(at_[sub][0], aL, tH0);
                MFMA(at_[sub][1], aH, tH1); MFMA(at_[sub][1], aH, tL1); MFMA(at_[sub][1], aL, tH1);
            }
        }
#pragma unroll
        for (int kk = 4; kk < 6; ++kk) {           // A = x (K 128..191), exact split
            short8 sH0 = *(const short8*)(Wp + kk * 16384);
            short8 sH1 = *(const short8*)(Wp + kk * 16384 + 128);
            short8 sL0 = *(const short8*)(Wp + kk * 16384 + 4096);
            short8 sL1 = *(const short8*)(Wp + kk * 16384 + 4096 + 128);
            short8 tH0 = *(const short8*)(Wp + kk * 16384 + 8192);
            short8 tH1 = *(const short8*)(Wp + kk * 16384 + 8192 + 128);
            short8 tL0 = *(const short8*)(Wp + kk * 16384 + 12288);
            short8 tL1 = *(const short8*)(Wp + kk * 16384 + 12288 + 128);
#pragma unroll
            for (int sub = 0; sub < 2; ++sub) {
                int row = i0 + sub * 16 + mr; if (row > n - 1) row = n - 1;
                short8 aH, aL;
                split8(x + (size_t)row * 64 + (kk - 4) * 32 + kc * 8, aH, aL);
                MFMA(as[sub][0], aH, sH0); MFMA(as[sub][0], aH, sL0); MFMA(as[sub][0], aL, sH0);
                MFMA(as[sub][1], aH, sH1); MFMA(as[sub][1], aH, sL1); MFMA(as[sub][1], aL, sH1);
                MFMA(at_[sub][0], aH, tH0); MFMA(at_[sub][0], aH, tL0); MFMA(at_[sub][0], aL, tH0);
                MFMA(at_[sub][1], aH, tH1); MFMA(at_[sub][1], aH, tL1); MFMA(at_[sub][1], aL, tH1);
            }
        }
    }
    __syncthreads();   // h2 LDS reads complete -> safe to alias gs

    // ---- gate epilogue ----
#pragma unroll
    for (int tt = 0; tt < 2; ++tt) {
        int c = (t0 + tt) * 16 + mr;
        float bsv = bsig[c], btv = btanh[c];
#pragma unroll
        for (int sub = 0; sub < 2; ++sub)
#pragma unroll
            for (int j = 0; j < 4; ++j) {
                int rl = sub * 16 + kc * 4 + j;
                float s = as[sub][tt][j] + bsv;
                s = fminf(fmaxf(s, -30.f), 30.f);
                float ta = at_[sub][tt][j] + btv;
                ta = fminf(fmaxf(ta, -15.f), 15.f);
                float e2 = __expf(2.f * ta);
                float th = (e2 - 1.f) / (e2 + 1.f);
                gs[rl * 128 + c] = th / (1.f + __expf(s));
            }
    }
    __syncthreads();

    // ---- run-compressed pooling ----
    int j = tid & 127;
    int m0 = (tid >> 7) * 16;
    float acc2 = 0.f;
    int cur = -1;
    for (int m = m0; m < m0 + 16; ++m) {
        int b = bS[m];
        if (b < 0) break;
        if (b != cur) {
            if (cur >= 0) atomicAdd(&pooled[(size_t)cur * 128 + j], acc2);
            cur = b;
            acc2 = 0.f;
        }
        acc2 += gs[m * 128 + j];
    }
    if (cur >= 0) atomicAdd(&pooled[(size_t)cur * 128 + j], acc2);
}

// ---------------------------------------------------------------------------
// Final per-graph MLP
// ---------------------------------------------------------------------------
__global__ __launch_bounds__(256) void mlp_kernel(
    const float* __restrict__ pooled,
    const float* __restrict__ Wf1, const float* __restrict__ bf1,
    const float* __restrict__ Wf2, const float* __restrict__ bf2,
    const float* __restrict__ Wout, const float* __restrict__ bout,
    float* __restrict__ out)
{
    __shared__ float p[128];
    __shared__ float f1[128];
    __shared__ float f2[258];
    __shared__ float red[4];

    int g = blockIdx.x;
    int tid = threadIdx.x;

    if (tid < 128) p[tid] = pooled[(size_t)g * 128 + tid];
    __syncthreads();

    if (tid < 128) {
        float a = bf1[tid];
        for (int k = 0; k < 128; ++k) a += p[k] * Wf1[k * 128 + tid];
        f1[tid] = LEAKY(a);
    }
    __syncthreads();

    for (int j = tid; j < 258; j += 256) {
        float a = bf2[j];
        for (int k = 0; k < 128; ++k) a += f1[k] * Wf2[k * 258 + j];
        f2[j] = LEAKY(a);
    }
    __syncthreads();

    float a = 0.f;
    for (int j = tid; j < 258; j += 256) a += f2[j] * Wout[j];
#pragma unroll
    for (int off = 32; off > 0; off >>= 1) a += __shfl_down(a, off, 64);
    if ((tid & 63) == 0) red[tid >> 6] = a;
    __syncthreads();
    if (tid == 0) {
        float v = red[0] + red[1] + red[2] + red[3] + bout[0];
        out[g] = 1.f / (1.f + expf(-v));
    }
}

// ---------------------------------------------------------------------------
extern "C" void kernel_launch(void* const* d_in, const int* in_sizes, int n_in,
                              void* d_out, int out_size, void* d_ws, size_t ws_size,
                              hipStream_t stream)
{
    const float* x     = (const float*)d_in[0];
    const int*   ei    = (const int*)d_in[1];
    const int*   batch = (const int*)d_in[2];
    const float* ea    = (const float*)d_in[3];
    const float* Wrel1 = (const float*)d_in[4];
    const float* brel1 = (const float*)d_in[5];
    const float* Wroot1= (const float*)d_in[6];
    const float* Wrel2 = (const float*)d_in[7];
    const float* brel2 = (const float*)d_in[8];
    const float* Wroot2= (const float*)d_in[9];
    const float* Wsig  = (const float*)d_in[10];
    const float* bsig  = (const float*)d_in[11];
    const float* Wtanh = (const float*)d_in[12];
    const float* btanh = (const float*)d_in[13];
    const float* Wf1   = (const float*)d_in[14];
    const float* bf1   = (const float*)d_in[15];
    const float* Wf2   = (const float*)d_in[16];
    const float* bf2   = (const float*)d_in[17];
    const float* Wout  = (const float*)d_in[18];
    const float* bout  = (const float*)d_in[19];

    int N = in_sizes[2];
    int E = in_sizes[3];

    char* base = (char*)d_ws;
    size_t off = 0;
    auto alloc = [&](size_t bytes) {
        char* p = base + off;
        off += (bytes + 255) & ~(size_t)255;
        return p;
    };
    ushort*   h1bf  = (ushort*)alloc((size_t)N * 128 * 2);
    ushort*   xbf   = (ushort*)alloc((size_t)N * 64 * 2);
    int*      rowptr= (int*)alloc((size_t)(N + 1) * 4);
    int*      cursor= (int*)alloc((size_t)N * 4);
    int*      bsum  = (int*)alloc(512 * 4);
    int*      csrc  = (int*)alloc((size_t)E * 4);
    float*    cwgt  = (float*)alloc((size_t)E * 4);
    ushort*   W1f   = (ushort*)alloc(32768 * 2);
    ushort*   W2f   = (ushort*)alloc(65536 * 2);
    ushort*   Wgf   = (ushort*)alloc(98304 * 2);
    float*    pooled= (float*)alloc(256 * 128 * 4);

    int eblk = (E + 255) / 256;
    int nblk1 = (N + 1023) / 1024;
    int cblk = (N + 31) / 32;

    hipMemsetAsync(cursor, 0, (size_t)N * sizeof(int), stream);
    hipMemsetAsync(pooled, 0, (size_t)256 * 128 * sizeof(float), stream);

    prep_weights_kernel<<<768, 256, 0, stream>>>(Wrel1, Wroot1, Wrel2, Wroot2,
                                                 Wsig, Wtanh, W1f, W2f, Wgf);
    xbf_kernel<<<(N * 16 + 255) / 256, 256, 0, stream>>>(x, xbf, N * 16);

    // ---- CSR build ----
    hist_kernel<<<eblk, 256, 0, stream>>>(ei, cursor, E);
    scan1_kernel<<<nblk1, 256, 0, stream>>>(cursor, rowptr, bsum, N);
    scan2_kernel<<<1, 512, 0, stream>>>(bsum, nblk1);
    scan3_kernel<<<(N + 255) / 256, 256, 0, stream>>>(rowptr, bsum, N, E);
    hipMemcpyAsync(cursor, rowptr, (size_t)N * sizeof(int),
                   hipMemcpyDeviceToDevice, stream);
    fill_kernel<<<eblk, 256, 0, stream>>>(ei, ea, cursor, csrc, cwgt, E);

    // ---- fused conv1 (gather + GEMM) ----
    conv1_fused_kernel<<<cblk, 256, 0, stream>>>(x, xbf, rowptr, csrc, cwgt,
                                                 W1f, brel1, h1bf, N);

    // ---- fused conv2 + gate + pool (gather + 2 GEMMs) ----
    conv2_gate_kernel<<<cblk, 256, 0, stream>>>(h1bf, x, rowptr, csrc, cwgt,
                                                W2f, brel2, Wgf, bsig, btanh,
                                                batch, pooled, N);

    // ---- final MLP ----
    mlp_kernel<<<256, 256, 0, stream>>>(pooled, Wf1, bf1, Wf2, bf2, Wout, bout,
                                        (float*)d_out);
}